// Round 1
// 681.529 us; speedup vs baseline: 1.0196x; 1.0196x over previous
//
#include <hip/hip_runtime.h>

typedef _Float16 f16;
typedef _Float16 f16x4 __attribute__((ext_vector_type(4)));
typedef _Float16 f16x8 __attribute__((ext_vector_type(8)));
typedef float    f32x4 __attribute__((ext_vector_type(4)));

#define NB    32
#define FEAT  320
#define NPTS  2048
#define M1    (NB * FEAT)          // 10240
#define KDIM  2048

// async global->LDS, 16B per lane. LDS dest = wave-uniform base + lane*16.
__device__ __forceinline__ void stage16(f16* lds_base, const f16* g) {
    __builtin_amdgcn_global_load_lds(
        (const __attribute__((address_space(1))) void*)g,
        (__attribute__((address_space(3))) void*)lds_base, 16, 0, 0);
}

// ---------------- cast fp32 -> f16 (straight) ----------------
__global__ void cast_k(const float* __restrict__ src, f16* __restrict__ dst, int n4) {
    int i = blockIdx.x * blockDim.x + threadIdx.x;
    int stride = gridDim.x * blockDim.x;
    for (; i < n4; i += stride) {
        f32x4 v = *(const f32x4*)(src + (size_t)i * 4);
        *(f16x4*)(dst + (size_t)i * 4) = __builtin_convertvector(v, f16x4);
    }
}

// ------------- transpose-cast W [o,i] fp32 -> WT [i,o] f16, z picks Wq/Wk --
__global__ void castT_k(const float* __restrict__ Wq, const float* __restrict__ Wk,
                        f16* __restrict__ WqT, f16* __restrict__ WkT) {
    __shared__ float T[64][65];
    const float* W = blockIdx.z ? Wk : Wq;
    f16* WT        = blockIdx.z ? WkT : WqT;
    const int i0 = blockIdx.x * 64, o0 = blockIdx.y * 64;
    const int tid = threadIdx.x;
#pragma unroll
    for (int j = 0; j < 4; ++j) {
        int e = j * 256 + tid, r = e >> 4, c4 = e & 15;
        f32x4 v = *(const f32x4*)&W[(size_t)(o0 + r) * 2048 + i0 + c4 * 4];
        *(f32x4*)&T[r][c4 * 4] = v;
    }
    __syncthreads();
#pragma unroll
    for (int j = 0; j < 2; ++j) {
        int e = j * 256 + tid, ir = e >> 3, oc8 = e & 7;
        f16x8 val;
#pragma unroll
        for (int k = 0; k < 8; ++k) val[k] = (f16)T[oc8 * 8 + k][ir];
        *(f16x8*)&WT[(size_t)(i0 + ir) * 2048 + o0 + oc8 * 8] = val;
    }
}

// ------- query [b,m,j] fp32 -> qf16 [b,m,j] + qT16 [b,j,m], both f16 -------
__global__ void cast_q_dual(const float* __restrict__ q, f16* __restrict__ qf16,
                            f16* __restrict__ qT16) {
    __shared__ float T[64][65];
    const int b = blockIdx.z;
    const int j0 = blockIdx.x * 64, m0 = blockIdx.y * 64;  // m0 in [0,320)
    const int tid = threadIdx.x;
#pragma unroll
    for (int j = 0; j < 4; ++j) {
        int e = j * 256 + tid, r = e >> 4, c4 = e & 15;
        size_t src = ((size_t)b * FEAT + m0 + r) * NPTS + j0 + c4 * 4;
        f32x4 v = *(const f32x4*)&q[src];
        *(f32x4*)&T[r][c4 * 4] = v;
        *(f16x4*)&qf16[src] = __builtin_convertvector(v, f16x4);
    }
    __syncthreads();
#pragma unroll
    for (int j = 0; j < 2; ++j) {
        int e = j * 256 + tid, jr = e >> 3, mc8 = e & 7;
        f16x8 val;
#pragma unroll
        for (int k = 0; k < 8; ++k) val[k] = (f16)T[mc8 * 8 + k][jr];
        *(f16x8*)&qT16[((size_t)b * NPTS + j0 + jr) * FEAT + m0 + mc8 * 8] = val;
    }
}

// ======== 128x128 bt-GEMM, BK=64 (split-k-half LDS): C = scale*A·B^T =======
// (kept for the 2048x2048 Gt GEMM: grid 16x16 = 256 blocks, already balanced)
__global__ __launch_bounds__(256, 2) void gemm128_f16(
    const f16* __restrict__ A, const f16* __restrict__ B, f16* __restrict__ C,
    float scale) {
    __shared__ f16 As[2 * 128 * 32];
    __shared__ f16 Bs[2 * 128 * 32];
    const int tid = threadIdx.x, lane = tid & 63, w = tid >> 6;
    const int wm = w >> 1, wn = w & 1, lo = lane & 15, q4 = lane >> 4;
    const long tm = (long)blockIdx.y * 128, tn = (long)blockIdx.x * 128;
    const f16* Abase = A + tm * KDIM;
    const f16* Bbase = B + tn * KDIM;
    f32x4 acc[4][4] = {};
    const int srow = lane >> 2, sch = (lane & 3) * 8;

    for (int k0 = 0; k0 < KDIM; k0 += 64) {
#pragma unroll
        for (int j = 0; j < 4; ++j) {
            const int u = w * 4 + j, h = u & 1, Rb = u >> 1;
            const int base = h * 4096 + Rb * 512;
            const long grow = Rb * 16 + srow;
            const long gk = k0 + h * 32 + sch;
            stage16(&As[base], Abase + grow * KDIM + gk);
            stage16(&Bs[base], Bbase + grow * KDIM + gk);
        }
        __syncthreads();
        f16x8 af[4][2], bf[4][2];
#pragma unroll
        for (int s = 0; s < 2; ++s) {
#pragma unroll
            for (int mi = 0; mi < 4; ++mi)
                af[mi][s] = *(const f16x8*)&As[s * 4096 + (wm * 64 + mi * 16 + lo) * 32 + q4 * 8];
#pragma unroll
            for (int ni = 0; ni < 4; ++ni)
                bf[ni][s] = *(const f16x8*)&Bs[s * 4096 + (wn * 64 + ni * 16 + lo) * 32 + q4 * 8];
        }
#pragma unroll
        for (int s = 0; s < 2; ++s)
#pragma unroll
            for (int mi = 0; mi < 4; ++mi)
#pragma unroll
                for (int ni = 0; ni < 4; ++ni)
                    acc[mi][ni] = __builtin_amdgcn_mfma_f32_16x16x32_f16(af[mi][s], bf[ni][s], acc[mi][ni], 0, 0, 0);
        __syncthreads();
    }
#pragma unroll
    for (int mi = 0; mi < 4; ++mi)
#pragma unroll
        for (int ni = 0; ni < 4; ++ni) {
            long gc = tn + wn * 64 + ni * 16 + lo;
#pragma unroll
            for (int r = 0; r < 4; ++r) {
                long gr = tm + wm * 64 + mi * 16 + q4 * 4 + r;
                C[gr * KDIM + gc] = (f16)(acc[mi][ni][r] * scale);
            }
        }
}

// ======= 320x256 8-wave phase-pipelined GEMM: C = A·B^T, K = 2048 =========
// BM=320 BN=256 BK=64; grid (8,32) = 256 blocks exactly (no quantization).
// LDS 144 KB double-buffered; 4 phases/K-tile {kh,mh}, 20 MFMA each, raw
// s_barrier (no vmcnt drain), setprio around MFMA clusters (T5).
// T2 swizzle: phys 16B slot = logical ^ (row&7); linear LDS dest +
// pre-swizzled per-lane GLOBAL source (rule #21), same XOR on ds_read.
// All 9 prefetch issues land in P0-P2; single vmcnt(0) at end of P3 is
// covered by >=1.5 phases of MFMA (counted-wait spirit of T4).
// RES=0: f16 out.  RES=1: fp32 out + fp32 residual add.
template<int RES>
__global__ __launch_bounds__(512, 2) void gemm_big(
    const f16* __restrict__ A, const f16* __restrict__ B,
    const float* __restrict__ resid, void* __restrict__ outp) {
    __shared__ f16 As[2][320 * 64];   // 80 KB
    __shared__ f16 Bs[2][256 * 64];   // 64 KB
    const int tid = threadIdx.x, lane = tid & 63, w = tid >> 6;
    const int wm = w >> 2, wn = w & 3, lo = lane & 15, q4 = lane >> 4;
    const int key = lo & 7;
    const long bm0 = (long)blockIdx.y * 320, bn0 = (long)blockIdx.x * 256;
    // staging source: row = stripe*8 + (lane>>3); col slot pre-swizzled
    const int r8 = lane >> 3, sw = (lane & 7) ^ r8;
    const f16* srcA = A + (bm0 + r8) * KDIM + sw * 8;
    const f16* srcB = B + (bn0 + r8) * KDIM + sw * 8;
    // fragment read offsets (f16 units): row*64 + physslot*8
    const int rA = (wm * 160 + lo) * 64;
    const int rB = (wn * 64 + lo) * 64;
    const int sl0 = (q4 ^ key) * 8;          // kh=0
    const int sl1 = ((q4 | 4) ^ key) * 8;    // kh=1

    f32x4 acc[10][4] = {};

    // prologue: K-tile 0 -> buf 0 (per wave: 5 A stripes + 4 B stripes)
#pragma unroll
    for (int i = 0; i < 5; ++i)
        stage16(&As[0][(w + 8 * i) * 512], srcA + (long)(w + 8 * i) * (8 * KDIM));
#pragma unroll
    for (int i = 0; i < 4; ++i)
        stage16(&Bs[0][(w + 8 * i) * 512], srcB + (long)(w + 8 * i) * (8 * KDIM));
    asm volatile("s_waitcnt vmcnt(0)" ::: "memory");
    __builtin_amdgcn_s_barrier();
    asm volatile("" ::: "memory");

    for (int t = 0; t < KDIM / 64; ++t) {
        const int cur = t & 1, nb = cur ^ 1;
        const long k0n = (long)(t + 1) * 64;
        const bool pf = (t + 1 < KDIM / 64);
        const f16* a = As[cur];
        const f16* b = Bs[cur];
        f16x8 af[5], bf[4];
        // -------- P0: kh=0 mh=0; prefetch A stripes 0-2 --------
#pragma unroll
        for (int ni = 0; ni < 4; ++ni) bf[ni] = *(const f16x8*)&b[rB + ni * 1024 + sl0];
#pragma unroll
        for (int i = 0; i < 5; ++i) af[i] = *(const f16x8*)&a[rA + i * 1024 + sl0];
        if (pf) {
#pragma unroll
            for (int i = 0; i < 3; ++i)
                stage16(&As[nb][(w + 8 * i) * 512], srcA + (long)(w + 8 * i) * (8 * KDIM) + k0n);
        }
        __builtin_amdgcn_s_barrier();
        __builtin_amdgcn_s_setprio(1);
#pragma unroll
        for (int i = 0; i < 5; ++i)
#pragma unroll
            for (int ni = 0; ni < 4; ++ni)
                acc[i][ni] = __builtin_amdgcn_mfma_f32_16x16x32_f16(af[i], bf[ni], acc[i][ni], 0, 0, 0);
        __builtin_amdgcn_s_setprio(0);
        __builtin_amdgcn_s_barrier();
        // -------- P1: kh=0 mh=1; prefetch A stripes 3-4 --------
#pragma unroll
        for (int i = 0; i < 5; ++i) af[i] = *(const f16x8*)&a[rA + (5 + i) * 1024 + sl0];
        if (pf) {
#pragma unroll
            for (int i = 3; i < 5; ++i)
                stage16(&As[nb][(w + 8 * i) * 512], srcA + (long)(w + 8 * i) * (8 * KDIM) + k0n);
        }
        __builtin_amdgcn_s_barrier();
        __builtin_amdgcn_s_setprio(1);
#pragma unroll
        for (int i = 0; i < 5; ++i)
#pragma unroll
            for (int ni = 0; ni < 4; ++ni)
                acc[5 + i][ni] = __builtin_amdgcn_mfma_f32_16x16x32_f16(af[i], bf[ni], acc[5 + i][ni], 0, 0, 0);
        __builtin_amdgcn_s_setprio(0);
        __builtin_amdgcn_s_barrier();
        // -------- P2: kh=1 mh=0; prefetch B stripes 0-3 --------
#pragma unroll
        for (int ni = 0; ni < 4; ++ni) bf[ni] = *(const f16x8*)&b[rB + ni * 1024 + sl1];
#pragma unroll
        for (int i = 0; i < 5; ++i) af[i] = *(const f16x8*)&a[rA + i * 1024 + sl1];
        if (pf) {
#pragma unroll
            for (int i = 0; i < 4; ++i)
                stage16(&Bs[nb][(w + 8 * i) * 512], srcB + (long)(w + 8 * i) * (8 * KDIM) + k0n);
        }
        __builtin_amdgcn_s_barrier();
        __builtin_amdgcn_s_setprio(1);
#pragma unroll
        for (int i = 0; i < 5; ++i)
#pragma unroll
            for (int ni = 0; ni < 4; ++ni)
                acc[i][ni] = __builtin_amdgcn_mfma_f32_16x16x32_f16(af[i], bf[ni], acc[i][ni], 0, 0, 0);
        __builtin_amdgcn_s_setprio(0);
        __builtin_amdgcn_s_barrier();
        // -------- P3: kh=1 mh=1; no prefetch; tile-end vmcnt(0) --------
#pragma unroll
        for (int i = 0; i < 5; ++i) af[i] = *(const f16x8*)&a[rA + (5 + i) * 1024 + sl1];
        __builtin_amdgcn_s_barrier();
        __builtin_amdgcn_s_setprio(1);
#pragma unroll
        for (int i = 0; i < 5; ++i)
#pragma unroll
            for (int ni = 0; ni < 4; ++ni)
                acc[5 + i][ni] = __builtin_amdgcn_mfma_f32_16x16x32_f16(af[i], bf[ni], acc[5 + i][ni], 0, 0, 0);
        __builtin_amdgcn_s_setprio(0);
        asm volatile("s_waitcnt vmcnt(0)" ::: "memory");
        __builtin_amdgcn_s_barrier();
        asm volatile("" ::: "memory");
    }

#pragma unroll
    for (int mi = 0; mi < 10; ++mi)
#pragma unroll
        for (int ni = 0; ni < 4; ++ni) {
            const long gc = bn0 + wn * 64 + ni * 16 + lo;
            const long gr0 = bm0 + wm * 160 + mi * 16 + q4 * 4;
            if (RES) {
                float* out = (float*)outp;
#pragma unroll
                for (int r = 0; r < 4; ++r) {
                    size_t idx = (size_t)(gr0 + r) * KDIM + gc;
                    out[idx] = acc[mi][ni][r] + resid[idx];
                }
            } else {
                f16* out = (f16*)outp;
#pragma unroll
                for (int r = 0; r < 4; ++r)
                    out[(size_t)(gr0 + r) * KDIM + gc] = (f16)acc[mi][ni][r];
            }
        }
}

// ==== 64x64 bt-GEMM batched, BK=64: attn[b,l,m] = sum_j T[l,j]·qf16[m,j] ===
__global__ __launch_bounds__(256, 2) void attn_gemm(
    const f16* __restrict__ T, const f16* __restrict__ qf16, float* __restrict__ attn) {
    __shared__ f16 As[2 * 64 * 32];
    __shared__ f16 Bs[2 * 64 * 32];
    const int b = blockIdx.z;
    const long tl = (long)blockIdx.y * 64, tmm = (long)blockIdx.x * 64;
    const int tid = threadIdx.x, lane = tid & 63, w = tid >> 6;
    const int wm = w >> 1, wn = w & 1, lo = lane & 15, q4 = lane >> 4;
    const f16* Abase = T + ((long)b * FEAT + tl) * KDIM;
    const f16* Bbase = qf16 + ((long)b * FEAT + tmm) * KDIM;
    const int srow = lane >> 2, sch = (lane & 3) * 8;
    f32x4 acc[2][2] = {};
    for (int k0 = 0; k0 < KDIM; k0 += 64) {
#pragma unroll
        for (int j = 0; j < 2; ++j) {
            const int u = w * 2 + j, h = u & 1, Rb = u >> 1;
            const int base = h * 2048 + Rb * 512;
            const long grow = Rb * 16 + srow;
            const long gk = k0 + h * 32 + sch;
            stage16(&As[base], Abase + grow * KDIM + gk);
            stage16(&Bs[base], Bbase + grow * KDIM + gk);
        }
        __syncthreads();
        f16x8 af[2][2], bf[2][2];
#pragma unroll
        for (int s = 0; s < 2; ++s) {
#pragma unroll
            for (int mi = 0; mi < 2; ++mi)
                af[mi][s] = *(const f16x8*)&As[s * 2048 + (wm * 32 + mi * 16 + lo) * 32 + q4 * 8];
#pragma unroll
            for (int ni = 0; ni < 2; ++ni)
                bf[ni][s] = *(const f16x8*)&Bs[s * 2048 + (wn * 32 + ni * 16 + lo) * 32 + q4 * 8];
        }
#pragma unroll
        for (int s = 0; s < 2; ++s)
#pragma unroll
            for (int mi = 0; mi < 2; ++mi)
#pragma unroll
                for (int ni = 0; ni < 2; ++ni)
                    acc[mi][ni] = __builtin_amdgcn_mfma_f32_16x16x32_f16(af[mi][s], bf[ni][s], acc[mi][ni], 0, 0, 0);
        __syncthreads();
    }
#pragma unroll
    for (int mi = 0; mi < 2; ++mi)
#pragma unroll
        for (int ni = 0; ni < 2; ++ni) {
            long gm = tmm + wn * 32 + ni * 16 + lo;
#pragma unroll
            for (int r = 0; r < 4; ++r) {
                long gl = tl + wm * 32 + mi * 16 + q4 * 4 + r;
                attn[(long)b * (FEAT * FEAT) + gl * FEAT + gm] = acc[mi][ni][r];
            }
        }
}

// == 64x128 bt-GEMM batched, K=320 BK=64: U[b,l,j] = sum_m P[l,m]·qT[j,m] ===
__global__ __launch_bounds__(256, 2) void u_gemm(
    const f16* __restrict__ P, const f16* __restrict__ qT16, f16* __restrict__ U) {
    __shared__ f16 As[2 * 64 * 32];     // 8 KB
    __shared__ f16 Bs[2 * 128 * 32];    // 16 KB
    const int b = blockIdx.z;
    const long tl = (long)blockIdx.y * 64, to = (long)blockIdx.x * 128;
    const int tid = threadIdx.x, lane = tid & 63, w = tid >> 6;
    const int wm = w >> 1, wn = w & 1, lo = lane & 15, q4 = lane >> 4;
    const f16* Abase = P + ((long)b * FEAT + tl) * FEAT;
    const f16* Bbase = qT16 + ((long)b * NPTS + to) * FEAT;
    const int srow = lane >> 2, sch = (lane & 3) * 8;
    f32x4 acc[2][4] = {};
    for (int k0 = 0; k0 < FEAT; k0 += 64) {   // 5 iterations
#pragma unroll
        for (int j = 0; j < 2; ++j) {          // A: 8 wave-units
            const int u = w * 2 + j, h = u & 1, Rb = u >> 1;
            stage16(&As[h * 2048 + Rb * 512],
                    Abase + (long)(Rb * 16 + srow) * FEAT + k0 + h * 32 + sch);
        }
#pragma unroll
        for (int j = 0; j < 4; ++j) {          // B: 16 wave-units
            const int u = w * 4 + j, h = u & 1, Rb = u >> 1;
            stage16(&Bs[h * 4096 + Rb * 512],
                    Bbase + (long)(Rb * 16 + srow) * FEAT + k0 + h * 32 + sch);
        }
        __syncthreads();
        f16x8 af[2][2], bf[4][2];
#pragma unroll
        for (int s = 0; s < 2; ++s) {
#pragma unroll
            for (int mi = 0; mi < 2; ++mi)
                af[mi][s] = *(const f16x8*)&As[s * 2048 + (wm * 32 + mi * 16 + lo) * 32 + q4 * 8];
#pragma unroll
            for (int ni = 0; ni < 4; ++ni)
                bf[ni][s] = *(const f16x8*)&Bs[s * 4096 + (wn * 64 + ni * 16 + lo) * 32 + q4 * 8];
        }
#pragma unroll
        for (int s = 0; s < 2; ++s)
#pragma unroll
            for (int mi = 0; mi < 2; ++mi)
#pragma unroll
                for (int ni = 0; ni < 4; ++ni)
                    acc[mi][ni] = __builtin_amdgcn_mfma_f32_16x16x32_f16(af[mi][s], bf[ni][s], acc[mi][ni], 0, 0, 0);
        __syncthreads();
    }
#pragma unroll
    for (int mi = 0; mi < 2; ++mi)
#pragma unroll
        for (int ni = 0; ni < 4; ++ni) {
            long go = to + wn * 64 + ni * 16 + lo;
#pragma unroll
            for (int r = 0; r < 4; ++r) {
                long gl = tl + wm * 32 + mi * 16 + q4 * 4 + r;
                U[((long)b * FEAT + gl) * NPTS + go] = (f16)acc[mi][ni][r];
            }
        }
}

// ---------------- softmax over rows of 320, fp32 in, f16 probs out ---------
__global__ void softmax_k(const float* __restrict__ attn, f16* __restrict__ probs) {
    const int r = blockIdx.x * 4 + (threadIdx.x >> 6);   // 10240 rows
    const int lane = threadIdx.x & 63;
    const float* row = attn + (size_t)r * FEAT;
    float v[5];
    float mx = -1e30f;
#pragma unroll
    for (int j = 0; j < 5; ++j) { v[j] = row[lane + j * 64]; mx = fmaxf(mx, v[j]); }
#pragma unroll
    for (int off = 32; off; off >>= 1) mx = fmaxf(mx, __shfl_xor(mx, off, 64));
    float s = 0.f;
#pragma unroll
    for (int j = 0; j < 5; ++j) { v[j] = __expf(v[j] - mx); s += v[j]; }
#pragma unroll
    for (int off = 32; off; off >>= 1) s += __shfl_xor(s, off, 64);
    const float inv = 1.f / s;
    f16* prow = probs + (size_t)r * FEAT;
#pragma unroll
    for (int j = 0; j < 5; ++j) prow[lane + j * 64] = (f16)(v[j] * inv);
}

// ---------------- in-place LayerNorm over FEAT (stride NPTS) ---------------
__global__ void ln_k(float* __restrict__ out, const float* __restrict__ gamma,
                     const float* __restrict__ beta) {
    __shared__ float g[FEAT], bt[FEAT];
    const int tid = threadIdx.x;
    for (int i = tid; i < FEAT; i += 256) { g[i] = gamma[i]; bt[i] = beta[i]; }
    __syncthreads();
    const int col = blockIdx.x * 256 + tid;     // 65536 columns
    const int b = col >> 11, o = col & 2047;
    float* base = out + (size_t)b * (FEAT * NPTS) + o;
    float s = 0.f, ss = 0.f;
    for (int l = 0; l < FEAT; ++l) {
        float x = base[(size_t)l * NPTS];
        s += x; ss += x * x;
    }
    const float mu = s * (1.f / FEAT);
    const float var = ss * (1.f / FEAT) - mu * mu;
    const float rstd = rsqrtf(var + 1e-5f);
    for (int l = 0; l < FEAT; ++l) {
        float x = base[(size_t)l * NPTS];
        base[(size_t)l * NPTS] = (x - mu) * rstd * g[l] + bt[l];
    }
}

extern "C" void kernel_launch(void* const* d_in, const int* in_sizes, int n_in,
                              void* d_out, int out_size, void* d_ws, size_t ws_size,
                              hipStream_t stream) {
    const float* query   = (const float*)d_in[0];
    const float* support = (const float*)d_in[1];
    const float* Wq      = (const float*)d_in[2];
    const float* Wk      = (const float*)d_in[3];
    const float* Wv      = (const float*)d_in[4];
    const float* gamma   = (const float*)d_in[5];
    const float* beta    = (const float*)d_in[6];
    float* out = (float*)d_out;

    char* ws = (char*)d_ws;
    const size_t SZ_W = (size_t)KDIM * KDIM * sizeof(f16);   //  8,388,608
    const size_t SZ_X = (size_t)M1 * KDIM * sizeof(f16);     // 41,943,040
    f16* wqT  = (f16*)(ws);                        // [i,o]
    f16* wkT  = (f16*)(ws + SZ_W);                 // [j,o]
    f16* wv16 = (f16*)(ws + 2 * SZ_W);             // [o,j] straight
    f16* gt   = (f16*)(ws + 3 * SZ_W);             // Gt[j,i] = G[i,j]/TEMP
    f16* sf16 = (f16*)(ws + 4 * SZ_W);             // support f16 [b*320, i]
    f16* qf16 = (f16*)(ws + 4 * SZ_W + SZ_X);      // [b,m,j]
    f16* qT16 = (f16*)(ws + 4 * SZ_W + 2 * SZ_X);  // [b,j,m]
    f16* T    = (f16*)(ws + 4 * SZ_W + 3 * SZ_X);  // [b*320, j]
    // overlays (stream-ordered; originals dead by first write):
    float* attn = (float*)(ws);                    // 13.1 MB over wqT+wkT (dead after g_gemm)
    f16*   P    = qf16;                            // probs (qf16 dead after attn_gemm)
    f16*   U    = sf16;                            // U[b,l,j] (sf16 dead after t_gemm)

    const float inv_temp = 0.05590169943749474f;   // 1/sqrt(320)

    castT_k<<<dim3(32, 32, 2), 256, 0, stream>>>(Wq, Wk, wqT, wkT);
    cast_k<<<1024, 256, 0, stream>>>(Wv, wv16, (KDIM * KDIM) / 4);
    cast_k<<<2048, 256, 0, stream>>>(support, sf16, (M1 * KDIM) / 4);
    cast_q_dual<<<dim3(32, 5, 32), 256, 0, stream>>>(query, qf16, qT16);

    // Gt[j,i] = (1/TEMP) * sum_o WkT[j,o] * WqT[i,o]  (2048^2, 256 blocks)
    gemm128_f16<<<dim3(16, 16), 256, 0, stream>>>(wkT, wqT, gt, inv_temp);
    // T[(b,l), j] = sum_i sf16[(b,l), i] * Gt[j, i]  -- 320x256 8-phase
    gemm_big<0><<<dim3(8, 32), 512, 0, stream>>>(sf16, gt, nullptr, T);
    // logits
    attn_gemm<<<dim3(5, 5, 32), 256, 0, stream>>>(T, qf16, attn);
    softmax_k<<<2560, 256, 0, stream>>>(attn, P);
    // U[b,l,j] = sum_m P[b,l,m] * qT16[b,j,m]
    u_gemm<<<dim3(16, 5, 32), 256, 0, stream>>>(P, qT16, U);
    // out = U * Wv^T + query  -- 320x256 8-phase + residual
    gemm_big<1><<<dim3(8, 32), 512, 0, stream>>>(U, wv16, query, out);
    ln_k<<<256, 256, 0, stream>>>(out, gamma, beta);
}

// Round 2
// 661.765 us; speedup vs baseline: 1.0500x; 1.0299x over previous
//
#include <hip/hip_runtime.h>

typedef _Float16 f16;
typedef _Float16 f16x4 __attribute__((ext_vector_type(4)));
typedef _Float16 f16x8 __attribute__((ext_vector_type(8)));
typedef float    f32x4 __attribute__((ext_vector_type(4)));

#define NB    32
#define FEAT  320
#define NPTS  2048
#define M1    (NB * FEAT)          // 10240
#define KDIM  2048

// async global->LDS, 16B per lane. LDS dest = wave-uniform base + lane*16.
__device__ __forceinline__ void stage16(f16* lds_base, const f16* g) {
    __builtin_amdgcn_global_load_lds(
        (const __attribute__((address_space(1))) void*)g,
        (__attribute__((address_space(3))) void*)lds_base, 16, 0, 0);
}

// ---------------- cast fp32 -> f16 (straight) ----------------
__global__ void cast_k(const float* __restrict__ src, f16* __restrict__ dst, int n4) {
    int i = blockIdx.x * blockDim.x + threadIdx.x;
    int stride = gridDim.x * blockDim.x;
    for (; i < n4; i += stride) {
        f32x4 v = *(const f32x4*)(src + (size_t)i * 4);
        *(f16x4*)(dst + (size_t)i * 4) = __builtin_convertvector(v, f16x4);
    }
}

// ------------- transpose-cast W [o,i] fp32 -> WT [i,o] f16, z picks Wq/Wk --
__global__ void castT_k(const float* __restrict__ Wq, const float* __restrict__ Wk,
                        f16* __restrict__ WqT, f16* __restrict__ WkT) {
    __shared__ float T[64][65];
    const float* W = blockIdx.z ? Wk : Wq;
    f16* WT        = blockIdx.z ? WkT : WqT;
    const int i0 = blockIdx.x * 64, o0 = blockIdx.y * 64;
    const int tid = threadIdx.x;
#pragma unroll
    for (int j = 0; j < 4; ++j) {
        int e = j * 256 + tid, r = e >> 4, c4 = e & 15;
        f32x4 v = *(const f32x4*)&W[(size_t)(o0 + r) * 2048 + i0 + c4 * 4];
        *(f32x4*)&T[r][c4 * 4] = v;
    }
    __syncthreads();
#pragma unroll
    for (int j = 0; j < 2; ++j) {
        int e = j * 256 + tid, ir = e >> 3, oc8 = e & 7;
        f16x8 val;
#pragma unroll
        for (int k = 0; k < 8; ++k) val[k] = (f16)T[oc8 * 8 + k][ir];
        *(f16x8*)&WT[(size_t)(i0 + ir) * 2048 + o0 + oc8 * 8] = val;
    }
}

// ------- query [b,m,j] fp32 -> qf16 [b,m,j] + qT16 [b,j,m], both f16 -------
__global__ void cast_q_dual(const float* __restrict__ q, f16* __restrict__ qf16,
                            f16* __restrict__ qT16) {
    __shared__ float T[64][65];
    const int b = blockIdx.z;
    const int j0 = blockIdx.x * 64, m0 = blockIdx.y * 64;  // m0 in [0,320)
    const int tid = threadIdx.x;
#pragma unroll
    for (int j = 0; j < 4; ++j) {
        int e = j * 256 + tid, r = e >> 4, c4 = e & 15;
        size_t src = ((size_t)b * FEAT + m0 + r) * NPTS + j0 + c4 * 4;
        f32x4 v = *(const f32x4*)&q[src];
        *(f32x4*)&T[r][c4 * 4] = v;
        *(f16x4*)&qf16[src] = __builtin_convertvector(v, f16x4);
    }
    __syncthreads();
#pragma unroll
    for (int j = 0; j < 2; ++j) {
        int e = j * 256 + tid, jr = e >> 3, mc8 = e & 7;
        f16x8 val;
#pragma unroll
        for (int k = 0; k < 8; ++k) val[k] = (f16)T[mc8 * 8 + k][jr];
        *(f16x8*)&qT16[((size_t)b * NPTS + j0 + jr) * FEAT + m0 + mc8 * 8] = val;
    }
}

// ======== 128x128 bt-GEMM, BK=64 (split-k-half LDS): C = scale*A·B^T =======
// (kept for the 2048x2048 Gt GEMM: grid 16x16 = 256 blocks, already balanced)
__global__ __launch_bounds__(256, 2) void gemm128_f16(
    const f16* __restrict__ A, const f16* __restrict__ B, f16* __restrict__ C,
    float scale) {
    __shared__ f16 As[2 * 128 * 32];
    __shared__ f16 Bs[2 * 128 * 32];
    const int tid = threadIdx.x, lane = tid & 63, w = tid >> 6;
    const int wm = w >> 1, wn = w & 1, lo = lane & 15, q4 = lane >> 4;
    const long tm = (long)blockIdx.y * 128, tn = (long)blockIdx.x * 128;
    const f16* Abase = A + tm * KDIM;
    const f16* Bbase = B + tn * KDIM;
    f32x4 acc[4][4] = {};
    const int srow = lane >> 2, sch = (lane & 3) * 8;

    for (int k0 = 0; k0 < KDIM; k0 += 64) {
#pragma unroll
        for (int j = 0; j < 4; ++j) {
            const int u = w * 4 + j, h = u & 1, Rb = u >> 1;
            const int base = h * 4096 + Rb * 512;
            const long grow = Rb * 16 + srow;
            const long gk = k0 + h * 32 + sch;
            stage16(&As[base], Abase + grow * KDIM + gk);
            stage16(&Bs[base], Bbase + grow * KDIM + gk);
        }
        __syncthreads();
        f16x8 af[4][2], bf[4][2];
#pragma unroll
        for (int s = 0; s < 2; ++s) {
#pragma unroll
            for (int mi = 0; mi < 4; ++mi)
                af[mi][s] = *(const f16x8*)&As[s * 4096 + (wm * 64 + mi * 16 + lo) * 32 + q4 * 8];
#pragma unroll
            for (int ni = 0; ni < 4; ++ni)
                bf[ni][s] = *(const f16x8*)&Bs[s * 4096 + (wn * 64 + ni * 16 + lo) * 32 + q4 * 8];
        }
#pragma unroll
        for (int s = 0; s < 2; ++s)
#pragma unroll
            for (int mi = 0; mi < 4; ++mi)
#pragma unroll
                for (int ni = 0; ni < 4; ++ni)
                    acc[mi][ni] = __builtin_amdgcn_mfma_f32_16x16x32_f16(af[mi][s], bf[ni][s], acc[mi][ni], 0, 0, 0);
        __syncthreads();
    }
#pragma unroll
    for (int mi = 0; mi < 4; ++mi)
#pragma unroll
        for (int ni = 0; ni < 4; ++ni) {
            long gc = tn + wn * 64 + ni * 16 + lo;
#pragma unroll
            for (int r = 0; r < 4; ++r) {
                long gr = tm + wm * 64 + mi * 16 + q4 * 4 + r;
                C[gr * KDIM + gc] = (f16)(acc[mi][ni][r] * scale);
            }
        }
}

// ======= 320x256 8-wave phase-pipelined GEMM: C = A·B^T, K = 2048 =========
// BM=320 BN=256 BK=64; grid (8,32) = 256 blocks exactly.
// COUNTED-vmcnt schedule (T4, m218): per-wave issue order per K-tile is
// [4x B, nA0 x A-P0rows, nA1 x A-P1rows] (nA0=3 w<4 else 2), so each
// phase's needs are a per-wave prefix:
//   tile boundary:  vmcnt(nA1) + barrier  -> B + A-P0 certified
//   after P0 MFMA:  vmcnt(4)   + barrier  -> A-P1 certified (4 new B in flight)
// Never drains to 0 in the main loop. Issue placement: B in P0, A-P0 in P1,
// A-P1 in P2 (>=2 phases of cover before each wait).
// T2 swizzle: phys 16B slot = logical ^ (row&7), linear LDS dest +
// pre-swizzled global source; same XOR on ds_read. T5 setprio around MFMA.
template<int RES>
__global__ __launch_bounds__(512, 2) void gemm_big(
    const f16* __restrict__ A, const f16* __restrict__ B,
    const float* __restrict__ resid, void* __restrict__ outp) {
    __shared__ f16 As[2][320 * 64];   // 80 KB
    __shared__ f16 Bs[2][256 * 64];   // 64 KB
    const int tid = threadIdx.x, lane = tid & 63, w = tid >> 6;
    const int wm = w >> 2, wn = w & 3, lo = lane & 15, q4 = lane >> 4;
    const int key = lo & 7;
    const int wu = __builtin_amdgcn_readfirstlane(w);   // wave-uniform SGPR
    const long bm0 = (long)blockIdx.y * 320, bn0 = (long)blockIdx.x * 256;
    // staging source: row = stripe*8 + (lane>>3); col slot pre-swizzled
    const int r8 = lane >> 3, sw = (lane & 7) ^ r8;
    const f16* srcA = A + (bm0 + r8) * KDIM + sw * 8;
    const f16* srcB = B + (bn0 + r8) * KDIM + sw * 8;
    // fragment read offsets (f16 units): row*64 + physslot*8
    const int rA = (wm * 160 + lo) * 64;
    const int rB = (wn * 64 + lo) * 64;
    const int sl0 = (q4 ^ key) * 8;          // kh=0
    const int sl1 = ((q4 | 4) ^ key) * 8;    // kh=1

    // ---- per-wave A-stripe ownership: a_str[0..nA0-1] are P0-need rows
    // (stripes {0..9,20..29}); a_str[nA0..4] are P1-need ({10..19,30..39}).
    int a_str[5], nA0;
    if (wu < 4) {
        nA0 = 3;
        const int b0 = 3 * wu;
        a_str[0] = (b0     < 10) ? b0     : b0 + 10;
        a_str[1] = (b0 + 1 < 10) ? b0 + 1 : b0 + 11;
        a_str[2] = (b0 + 2 < 10) ? b0 + 2 : b0 + 12;
        const int c0 = 2 * wu;               // < 10 always
        a_str[3] = c0 + 10;
        a_str[4] = c0 + 11;
    } else {
        nA0 = 2;
        const int b0 = 12 + 2 * (wu - 4);    // >= 10 always
        a_str[0] = b0 + 10;
        a_str[1] = b0 + 11;
        const int c0 = 8 + 3 * (wu - 4);
        a_str[2] = (c0     < 10) ? c0 + 10 : c0 + 20;
        a_str[3] = (c0 + 1 < 10) ? c0 + 11 : c0 + 21;
        a_str[4] = (c0 + 2 < 10) ? c0 + 12 : c0 + 22;
    }

    f32x4 acc[10][4] = {};

    // prologue: K-tile 0 -> buf 0, in counted issue order [B x4, A x5]
#pragma unroll
    for (int i = 0; i < 4; ++i)
        stage16(&Bs[0][(w + 8 * i) * 512], srcB + (long)(w + 8 * i) * (8 * KDIM));
#pragma unroll
    for (int i = 0; i < 5; ++i)
        stage16(&As[0][a_str[i] * 512], srcA + (long)a_str[i] * (8 * KDIM));
    if (wu < 4) asm volatile("s_waitcnt vmcnt(2)" ::: "memory");
    else        asm volatile("s_waitcnt vmcnt(3)" ::: "memory");
    __builtin_amdgcn_s_barrier();
    asm volatile("" ::: "memory");

    for (int t = 0; t < KDIM / 64; ++t) {
        const int cur = t & 1, nb = cur ^ 1;
        const long k0n = (long)(t + 1) * 64;
        const bool pf = (t + 1 < KDIM / 64);
        const f16* a = As[cur];
        const f16* b = Bs[cur];
        f16x8 af[5], bf[4];
        // -------- P0: kh=0 mh=0; issue next-tile B (4) --------
#pragma unroll
        for (int ni = 0; ni < 4; ++ni) bf[ni] = *(const f16x8*)&b[rB + ni * 1024 + sl0];
#pragma unroll
        for (int i = 0; i < 5; ++i) af[i] = *(const f16x8*)&a[rA + i * 1024 + sl0];
        if (pf) {
#pragma unroll
            for (int i = 0; i < 4; ++i)
                stage16(&Bs[nb][(w + 8 * i) * 512], srcB + (long)(w + 8 * i) * (8 * KDIM) + k0n);
        }
        __builtin_amdgcn_s_barrier();
        __builtin_amdgcn_s_setprio(1);
#pragma unroll
        for (int i = 0; i < 5; ++i)
#pragma unroll
            for (int ni = 0; ni < 4; ++ni)
                acc[i][ni] = __builtin_amdgcn_mfma_f32_16x16x32_f16(af[i], bf[ni], acc[i][ni], 0, 0, 0);
        __builtin_amdgcn_s_setprio(0);
        // counted wait: A-P1 rows of THIS tile must land; 4 new B stay in flight
        if (pf) asm volatile("s_waitcnt vmcnt(4)" ::: "memory");
        else    asm volatile("s_waitcnt vmcnt(0)" ::: "memory");
        __builtin_amdgcn_s_barrier();
        asm volatile("" ::: "memory");
        // -------- P1: kh=0 mh=1; issue next-tile A-P0 (nA0) --------
#pragma unroll
        for (int i = 0; i < 5; ++i) af[i] = *(const f16x8*)&a[rA + (5 + i) * 1024 + sl0];
        if (pf) {
#pragma unroll
            for (int i = 0; i < 5; ++i)
                if (i < nA0)
                    stage16(&As[nb][a_str[i] * 512], srcA + (long)a_str[i] * (8 * KDIM) + k0n);
        }
        __builtin_amdgcn_s_barrier();
        __builtin_amdgcn_s_setprio(1);
#pragma unroll
        for (int i = 0; i < 5; ++i)
#pragma unroll
            for (int ni = 0; ni < 4; ++ni)
                acc[5 + i][ni] = __builtin_amdgcn_mfma_f32_16x16x32_f16(af[i], bf[ni], acc[5 + i][ni], 0, 0, 0);
        __builtin_amdgcn_s_setprio(0);
        __builtin_amdgcn_s_barrier();
        // -------- P2: kh=1 mh=0; issue next-tile A-P1 (nA1) --------
#pragma unroll
        for (int ni = 0; ni < 4; ++ni) bf[ni] = *(const f16x8*)&b[rB + ni * 1024 + sl1];
#pragma unroll
        for (int i = 0; i < 5; ++i) af[i] = *(const f16x8*)&a[rA + i * 1024 + sl1];
        if (pf) {
#pragma unroll
            for (int i = 0; i < 5; ++i)
                if (i >= nA0)
                    stage16(&As[nb][a_str[i] * 512], srcA + (long)a_str[i] * (8 * KDIM) + k0n);
        }
        __builtin_amdgcn_s_barrier();
        __builtin_amdgcn_s_setprio(1);
#pragma unroll
        for (int i = 0; i < 5; ++i)
#pragma unroll
            for (int ni = 0; ni < 4; ++ni)
                acc[i][ni] = __builtin_amdgcn_mfma_f32_16x16x32_f16(af[i], bf[ni], acc[i][ni], 0, 0, 0);
        __builtin_amdgcn_s_setprio(0);
        __builtin_amdgcn_s_barrier();
        // -------- P3: kh=1 mh=1; boundary counted wait --------
#pragma unroll
        for (int i = 0; i < 5; ++i) af[i] = *(const f16x8*)&a[rA + (5 + i) * 1024 + sl1];
        __builtin_amdgcn_s_barrier();
        __builtin_amdgcn_s_setprio(1);
#pragma unroll
        for (int i = 0; i < 5; ++i)
#pragma unroll
            for (int ni = 0; ni < 4; ++ni)
                acc[5 + i][ni] = __builtin_amdgcn_mfma_f32_16x16x32_f16(af[i], bf[ni], acc[5 + i][ni], 0, 0, 0);
        __builtin_amdgcn_s_setprio(0);
        if (pf) {
            // boundary: next tile's B + A-P0 must land; its A-P1 stays in flight
            if (wu < 4) asm volatile("s_waitcnt vmcnt(2)" ::: "memory");
            else        asm volatile("s_waitcnt vmcnt(3)" ::: "memory");
            __builtin_amdgcn_s_barrier();
            asm volatile("" ::: "memory");
        }
    }

#pragma unroll
    for (int mi = 0; mi < 10; ++mi)
#pragma unroll
        for (int ni = 0; ni < 4; ++ni) {
            const long gc = bn0 + wn * 64 + ni * 16 + lo;
            const long gr0 = bm0 + wm * 160 + mi * 16 + q4 * 4;
            if (RES) {
                float* out = (float*)outp;
#pragma unroll
                for (int r = 0; r < 4; ++r) {
                    size_t idx = (size_t)(gr0 + r) * KDIM + gc;
                    out[idx] = acc[mi][ni][r] + resid[idx];
                }
            } else {
                f16* out = (f16*)outp;
#pragma unroll
                for (int r = 0; r < 4; ++r)
                    out[(size_t)(gr0 + r) * KDIM + gc] = (f16)acc[mi][ni][r];
            }
        }
}

// ==== 64x64 bt-GEMM batched, BK=64: attn[b,l,m] = sum_j T[l,j]·qf16[m,j] ===
__global__ __launch_bounds__(256, 2) void attn_gemm(
    const f16* __restrict__ T, const f16* __restrict__ qf16, float* __restrict__ attn) {
    __shared__ f16 As[2 * 64 * 32];
    __shared__ f16 Bs[2 * 64 * 32];
    const int b = blockIdx.z;
    const long tl = (long)blockIdx.y * 64, tmm = (long)blockIdx.x * 64;
    const int tid = threadIdx.x, lane = tid & 63, w = tid >> 6;
    const int wm = w >> 1, wn = w & 1, lo = lane & 15, q4 = lane >> 4;
    const f16* Abase = T + ((long)b * FEAT + tl) * KDIM;
    const f16* Bbase = qf16 + ((long)b * FEAT + tmm) * KDIM;
    const int srow = lane >> 2, sch = (lane & 3) * 8;
    f32x4 acc[2][2] = {};
    for (int k0 = 0; k0 < KDIM; k0 += 64) {
#pragma unroll
        for (int j = 0; j < 2; ++j) {
            const int u = w * 2 + j, h = u & 1, Rb = u >> 1;
            const int base = h * 2048 + Rb * 512;
            const long grow = Rb * 16 + srow;
            const long gk = k0 + h * 32 + sch;
            stage16(&As[base], Abase + grow * KDIM + gk);
            stage16(&Bs[base], Bbase + grow * KDIM + gk);
        }
        __syncthreads();
        f16x8 af[2][2], bf[2][2];
#pragma unroll
        for (int s = 0; s < 2; ++s) {
#pragma unroll
            for (int mi = 0; mi < 2; ++mi)
                af[mi][s] = *(const f16x8*)&As[s * 2048 + (wm * 32 + mi * 16 + lo) * 32 + q4 * 8];
#pragma unroll
            for (int ni = 0; ni < 2; ++ni)
                bf[ni][s] = *(const f16x8*)&Bs[s * 2048 + (wn * 32 + ni * 16 + lo) * 32 + q4 * 8];
        }
#pragma unroll
        for (int s = 0; s < 2; ++s)
#pragma unroll
            for (int mi = 0; mi < 2; ++mi)
#pragma unroll
                for (int ni = 0; ni < 2; ++ni)
                    acc[mi][ni] = __builtin_amdgcn_mfma_f32_16x16x32_f16(af[mi][s], bf[ni][s], acc[mi][ni], 0, 0, 0);
        __syncthreads();
    }
#pragma unroll
    for (int mi = 0; mi < 2; ++mi)
#pragma unroll
        for (int ni = 0; ni < 2; ++ni) {
            long gm = tmm + wn * 32 + ni * 16 + lo;
#pragma unroll
            for (int r = 0; r < 4; ++r) {
                long gl = tl + wm * 32 + mi * 16 + q4 * 4 + r;
                attn[(long)b * (FEAT * FEAT) + gl * FEAT + gm] = acc[mi][ni][r];
            }
        }
}

// == 64x128 bt-GEMM batched, K=320 BK=64: U[b,l,j] = sum_m P[l,m]·qT[j,m] ===
__global__ __launch_bounds__(256, 2) void u_gemm(
    const f16* __restrict__ P, const f16* __restrict__ qT16, f16* __restrict__ U) {
    __shared__ f16 As[2 * 64 * 32];     // 8 KB
    __shared__ f16 Bs[2 * 128 * 32];    // 16 KB
    const int b = blockIdx.z;
    const long tl = (long)blockIdx.y * 64, to = (long)blockIdx.x * 128;
    const int tid = threadIdx.x, lane = tid & 63, w = tid >> 6;
    const int wm = w >> 1, wn = w & 1, lo = lane & 15, q4 = lane >> 4;
    const f16* Abase = P + ((long)b * FEAT + tl) * FEAT;
    const f16* Bbase = qT16 + ((long)b * NPTS + to) * FEAT;
    const int srow = lane >> 2, sch = (lane & 3) * 8;
    f32x4 acc[2][4] = {};
    for (int k0 = 0; k0 < FEAT; k0 += 64) {   // 5 iterations
#pragma unroll
        for (int j = 0; j < 2; ++j) {          // A: 8 wave-units
            const int u = w * 2 + j, h = u & 1, Rb = u >> 1;
            stage16(&As[h * 2048 + Rb * 512],
                    Abase + (long)(Rb * 16 + srow) * FEAT + k0 + h * 32 + sch);
        }
#pragma unroll
        for (int j = 0; j < 4; ++j) {          // B: 16 wave-units
            const int u = w * 4 + j, h = u & 1, Rb = u >> 1;
            stage16(&Bs[h * 4096 + Rb * 512],
                    Bbase + (long)(Rb * 16 + srow) * FEAT + k0 + h * 32 + sch);
        }
        __syncthreads();
        f16x8 af[2][2], bf[4][2];
#pragma unroll
        for (int s = 0; s < 2; ++s) {
#pragma unroll
            for (int mi = 0; mi < 2; ++mi)
                af[mi][s] = *(const f16x8*)&As[s * 2048 + (wm * 32 + mi * 16 + lo) * 32 + q4 * 8];
#pragma unroll
            for (int ni = 0; ni < 4; ++ni)
                bf[ni][s] = *(const f16x8*)&Bs[s * 4096 + (wn * 64 + ni * 16 + lo) * 32 + q4 * 8];
        }
#pragma unroll
        for (int s = 0; s < 2; ++s)
#pragma unroll
            for (int mi = 0; mi < 2; ++mi)
#pragma unroll
                for (int ni = 0; ni < 4; ++ni)
                    acc[mi][ni] = __builtin_amdgcn_mfma_f32_16x16x32_f16(af[mi][s], bf[ni][s], acc[mi][ni], 0, 0, 0);
        __syncthreads();
    }
#pragma unroll
    for (int mi = 0; mi < 2; ++mi)
#pragma unroll
        for (int ni = 0; ni < 4; ++ni) {
            long go = to + wn * 64 + ni * 16 + lo;
#pragma unroll
            for (int r = 0; r < 4; ++r) {
                long gl = tl + wm * 32 + mi * 16 + q4 * 4 + r;
                U[((long)b * FEAT + gl) * NPTS + go] = (f16)acc[mi][ni][r];
            }
        }
}

// ---------------- softmax over rows of 320, fp32 in, f16 probs out ---------
__global__ void softmax_k(const float* __restrict__ attn, f16* __restrict__ probs) {
    const int r = blockIdx.x * 4 + (threadIdx.x >> 6);   // 10240 rows
    const int lane = threadIdx.x & 63;
    const float* row = attn + (size_t)r * FEAT;
    float v[5];
    float mx = -1e30f;
#pragma unroll
    for (int j = 0; j < 5; ++j) { v[j] = row[lane + j * 64]; mx = fmaxf(mx, v[j]); }
#pragma unroll
    for (int off = 32; off; off >>= 1) mx = fmaxf(mx, __shfl_xor(mx, off, 64));
    float s = 0.f;
#pragma unroll
    for (int j = 0; j < 5; ++j) { v[j] = __expf(v[j] - mx); s += v[j]; }
#pragma unroll
    for (int off = 32; off; off >>= 1) s += __shfl_xor(s, off, 64);
    const float inv = 1.f / s;
    f16* prow = probs + (size_t)r * FEAT;
#pragma unroll
    for (int j = 0; j < 5; ++j) prow[lane + j * 64] = (f16)(v[j] * inv);
}

// ---------------- in-place LayerNorm over FEAT (stride NPTS) ---------------
__global__ void ln_k(float* __restrict__ out, const float* __restrict__ gamma,
                     const float* __restrict__ beta) {
    __shared__ float g[FEAT], bt[FEAT];
    const int tid = threadIdx.x;
    for (int i = tid; i < FEAT; i += 256) { g[i] = gamma[i]; bt[i] = beta[i]; }
    __syncthreads();
    const int col = blockIdx.x * 256 + tid;     // 65536 columns
    const int b = col >> 11, o = col & 2047;
    float* base = out + (size_t)b * (FEAT * NPTS) + o;
    float s = 0.f, ss = 0.f;
    for (int l = 0; l < FEAT; ++l) {
        float x = base[(size_t)l * NPTS];
        s += x; ss += x * x;
    }
    const float mu = s * (1.f / FEAT);
    const float var = ss * (1.f / FEAT) - mu * mu;
    const float rstd = rsqrtf(var + 1e-5f);
    for (int l = 0; l < FEAT; ++l) {
        float x = base[(size_t)l * NPTS];
        base[(size_t)l * NPTS] = (x - mu) * rstd * g[l] + bt[l];
    }
}

extern "C" void kernel_launch(void* const* d_in, const int* in_sizes, int n_in,
                              void* d_out, int out_size, void* d_ws, size_t ws_size,
                              hipStream_t stream) {
    const float* query   = (const float*)d_in[0];
    const float* support = (const float*)d_in[1];
    const float* Wq      = (const float*)d_in[2];
    const float* Wk      = (const float*)d_in[3];
    const float* Wv      = (const float*)d_in[4];
    const float* gamma   = (const float*)d_in[5];
    const float* beta    = (const float*)d_in[6];
    float* out = (float*)d_out;

    char* ws = (char*)d_ws;
    const size_t SZ_W = (size_t)KDIM * KDIM * sizeof(f16);   //  8,388,608
    const size_t SZ_X = (size_t)M1 * KDIM * sizeof(f16);     // 41,943,040
    f16* wqT  = (f16*)(ws);                        // [i,o]
    f16* wkT  = (f16*)(ws + SZ_W);                 // [j,o]
    f16* wv16 = (f16*)(ws + 2 * SZ_W);             // [o,j] straight
    f16* gt   = (f16*)(ws + 3 * SZ_W);             // Gt[j,i] = G[i,j]/TEMP
    f16* sf16 = (f16*)(ws + 4 * SZ_W);             // support f16 [b*320, i]
    f16* qf16 = (f16*)(ws + 4 * SZ_W + SZ_X);      // [b,m,j]
    f16* qT16 = (f16*)(ws + 4 * SZ_W + 2 * SZ_X);  // [b,j,m]
    f16* T    = (f16*)(ws + 4 * SZ_W + 3 * SZ_X);  // [b*320, j]
    // overlays (stream-ordered; originals dead by first write):
    float* attn = (float*)(ws);                    // 13.1 MB over wqT+wkT (dead after g_gemm)
    f16*   P    = qf16;                            // probs (qf16 dead after attn_gemm)
    f16*   U    = sf16;                            // U[b,l,j] (sf16 dead after t_gemm)

    const float inv_temp = 0.05590169943749474f;   // 1/sqrt(320)

    castT_k<<<dim3(32, 32, 2), 256, 0, stream>>>(Wq, Wk, wqT, wkT);
    cast_k<<<1024, 256, 0, stream>>>(Wv, wv16, (KDIM * KDIM) / 4);
    cast_k<<<2048, 256, 0, stream>>>(support, sf16, (M1 * KDIM) / 4);
    cast_q_dual<<<dim3(32, 5, 32), 256, 0, stream>>>(query, qf16, qT16);

    // Gt[j,i] = (1/TEMP) * sum_o WkT[j,o] * WqT[i,o]  (2048^2, 256 blocks)
    gemm128_f16<<<dim3(16, 16), 256, 0, stream>>>(wkT, wqT, gt, inv_temp);
    // T[(b,l), j] = sum_i sf16[(b,l), i] * Gt[j, i]  -- counted-vmcnt 320x256
    gemm_big<0><<<dim3(8, 32), 512, 0, stream>>>(sf16, gt, nullptr, T);
    // logits
    attn_gemm<<<dim3(5, 5, 32), 256, 0, stream>>>(T, qf16, attn);
    softmax_k<<<2560, 256, 0, stream>>>(attn, P);
    // U[b,l,j] = sum_m P[b,l,m] * qT16[b,j,m]
    u_gemm<<<dim3(16, 5, 32), 256, 0, stream>>>(P, qT16, U);
    // out = U * Wv^T + query  -- counted-vmcnt 320x256 + residual
    gemm_big<1><<<dim3(8, 32), 512, 0, stream>>>(U, wv16, query, out);
    ln_k<<<256, 256, 0, stream>>>(out, gamma, beta);
}

// Round 3
// 660.748 us; speedup vs baseline: 1.0517x; 1.0015x over previous
//
#include <hip/hip_runtime.h>

typedef _Float16 f16;
typedef _Float16 f16x4 __attribute__((ext_vector_type(4)));
typedef _Float16 f16x8 __attribute__((ext_vector_type(8)));
typedef float    f32x4 __attribute__((ext_vector_type(4)));

#define NB    32
#define FEAT  320
#define NPTS  2048
#define M1    (NB * FEAT)          // 10240
#define KDIM  2048

// async global->LDS, 16B per lane. LDS dest = wave-uniform base + lane*16.
__device__ __forceinline__ void stage16(f16* lds_base, const f16* g) {
    __builtin_amdgcn_global_load_lds(
        (const __attribute__((address_space(1))) void*)g,
        (__attribute__((address_space(3))) void*)lds_base, 16, 0, 0);
}

// ---------------- cast fp32 -> f16 (straight) ----------------
__global__ void cast_k(const float* __restrict__ src, f16* __restrict__ dst, int n4) {
    int i = blockIdx.x * blockDim.x + threadIdx.x;
    int stride = gridDim.x * blockDim.x;
    for (; i < n4; i += stride) {
        f32x4 v = *(const f32x4*)(src + (size_t)i * 4);
        *(f16x4*)(dst + (size_t)i * 4) = __builtin_convertvector(v, f16x4);
    }
}

// ------------- transpose-cast W [o,i] fp32 -> WT [i,o] f16, z picks Wq/Wk --
__global__ void castT_k(const float* __restrict__ Wq, const float* __restrict__ Wk,
                        f16* __restrict__ WqT, f16* __restrict__ WkT) {
    __shared__ float T[64][65];
    const float* W = blockIdx.z ? Wk : Wq;
    f16* WT        = blockIdx.z ? WkT : WqT;
    const int i0 = blockIdx.x * 64, o0 = blockIdx.y * 64;
    const int tid = threadIdx.x;
#pragma unroll
    for (int j = 0; j < 4; ++j) {
        int e = j * 256 + tid, r = e >> 4, c4 = e & 15;
        f32x4 v = *(const f32x4*)&W[(size_t)(o0 + r) * 2048 + i0 + c4 * 4];
        *(f32x4*)&T[r][c4 * 4] = v;
    }
    __syncthreads();
#pragma unroll
    for (int j = 0; j < 2; ++j) {
        int e = j * 256 + tid, ir = e >> 3, oc8 = e & 7;
        f16x8 val;
#pragma unroll
        for (int k = 0; k < 8; ++k) val[k] = (f16)T[oc8 * 8 + k][ir];
        *(f16x8*)&WT[(size_t)(i0 + ir) * 2048 + o0 + oc8 * 8] = val;
    }
}

// ------- query [b,m,j] fp32 -> qf16 [b,m,j] + qT16 [b,j,m], both f16 -------
__global__ void cast_q_dual(const float* __restrict__ q, f16* __restrict__ qf16,
                            f16* __restrict__ qT16) {
    __shared__ float T[64][65];
    const int b = blockIdx.z;
    const int j0 = blockIdx.x * 64, m0 = blockIdx.y * 64;  // m0 in [0,320)
    const int tid = threadIdx.x;
#pragma unroll
    for (int j = 0; j < 4; ++j) {
        int e = j * 256 + tid, r = e >> 4, c4 = e & 15;
        size_t src = ((size_t)b * FEAT + m0 + r) * NPTS + j0 + c4 * 4;
        f32x4 v = *(const f32x4*)&q[src];
        *(f32x4*)&T[r][c4 * 4] = v;
        *(f16x4*)&qf16[src] = __builtin_convertvector(v, f16x4);
    }
    __syncthreads();
#pragma unroll
    for (int j = 0; j < 2; ++j) {
        int e = j * 256 + tid, jr = e >> 3, mc8 = e & 7;
        f16x8 val;
#pragma unroll
        for (int k = 0; k < 8; ++k) val[k] = (f16)T[mc8 * 8 + k][jr];
        *(f16x8*)&qT16[((size_t)b * NPTS + j0 + jr) * FEAT + m0 + mc8 * 8] = val;
    }
}

// ======== 128x128 bt-GEMM, BK=64 (split-k-half LDS): C = scale*A·B^T =======
// (kept for the 2048x2048 Gt GEMM: grid 16x16 = 256 blocks, already balanced)
__global__ __launch_bounds__(256, 2) void gemm128_f16(
    const f16* __restrict__ A, const f16* __restrict__ B, f16* __restrict__ C,
    float scale) {
    __shared__ f16 As[2 * 128 * 32];
    __shared__ f16 Bs[2 * 128 * 32];
    const int tid = threadIdx.x, lane = tid & 63, w = tid >> 6;
    const int wm = w >> 1, wn = w & 1, lo = lane & 15, q4 = lane >> 4;
    const long tm = (long)blockIdx.y * 128, tn = (long)blockIdx.x * 128;
    const f16* Abase = A + tm * KDIM;
    const f16* Bbase = B + tn * KDIM;
    f32x4 acc[4][4] = {};
    const int srow = lane >> 2, sch = (lane & 3) * 8;

    for (int k0 = 0; k0 < KDIM; k0 += 64) {
#pragma unroll
        for (int j = 0; j < 4; ++j) {
            const int u = w * 4 + j, h = u & 1, Rb = u >> 1;
            const int base = h * 4096 + Rb * 512;
            const long grow = Rb * 16 + srow;
            const long gk = k0 + h * 32 + sch;
            stage16(&As[base], Abase + grow * KDIM + gk);
            stage16(&Bs[base], Bbase + grow * KDIM + gk);
        }
        __syncthreads();
        f16x8 af[4][2], bf[4][2];
#pragma unroll
        for (int s = 0; s < 2; ++s) {
#pragma unroll
            for (int mi = 0; mi < 4; ++mi)
                af[mi][s] = *(const f16x8*)&As[s * 4096 + (wm * 64 + mi * 16 + lo) * 32 + q4 * 8];
#pragma unroll
            for (int ni = 0; ni < 4; ++ni)
                bf[ni][s] = *(const f16x8*)&Bs[s * 4096 + (wn * 64 + ni * 16 + lo) * 32 + q4 * 8];
        }
#pragma unroll
        for (int s = 0; s < 2; ++s)
#pragma unroll
            for (int mi = 0; mi < 4; ++mi)
#pragma unroll
                for (int ni = 0; ni < 4; ++ni)
                    acc[mi][ni] = __builtin_amdgcn_mfma_f32_16x16x32_f16(af[mi][s], bf[ni][s], acc[mi][ni], 0, 0, 0);
        __syncthreads();
    }
#pragma unroll
    for (int mi = 0; mi < 4; ++mi)
#pragma unroll
        for (int ni = 0; ni < 4; ++ni) {
            long gc = tn + wn * 64 + ni * 16 + lo;
#pragma unroll
            for (int r = 0; r < 4; ++r) {
                long gr = tm + wm * 64 + mi * 16 + q4 * 4 + r;
                C[gr * KDIM + gc] = (f16)(acc[mi][ni][r] * scale);
            }
        }
}

// ======= 320x256 8-wave phase-pipelined GEMM: C = A·B^T, K = 2048 =========
// BM=320 BN=256 BK=64; grid (8,32) = 256 blocks exactly.
// COUNTED-vmcnt schedule (T4) with MINIMAL barriers (2 per K-tile):
// within a tile all ds_reads hit buf[cur] and all stage16 writes hit
// buf[nb], so the only sync points are the two write-certification
// waits. Dropping the per-phase lockstep barriers lets ds_read bursts
// of one wave overlap MFMA of another (and lets the compiler pipeline
// P2/P3 reads into P1's MFMA cluster).
//   mid-tile:  vmcnt(4)      + barrier -> this tile's A-P1 certified
//   boundary:  vmcnt(nA1pfx) + barrier -> next tile's B + A-P0 certified
// Per-wave issue order per tile: [4x B, nA0 x A-P0, nA1 x A-P1].
// T2 swizzle: phys 16B slot = logical ^ (row&7), linear LDS dest +
// pre-swizzled global source; same XOR on ds_read. T5 setprio on MFMA.
template<int RES>
__global__ __launch_bounds__(512, 2) void gemm_big(
    const f16* __restrict__ A, const f16* __restrict__ B,
    const float* __restrict__ resid, void* __restrict__ outp) {
    __shared__ f16 As[2][320 * 64];   // 80 KB
    __shared__ f16 Bs[2][256 * 64];   // 64 KB
    const int tid = threadIdx.x, lane = tid & 63, w = tid >> 6;
    const int wm = w >> 2, wn = w & 3, lo = lane & 15, q4 = lane >> 4;
    const int key = lo & 7;
    const int wu = __builtin_amdgcn_readfirstlane(w);   // wave-uniform SGPR
    const long bm0 = (long)blockIdx.y * 320, bn0 = (long)blockIdx.x * 256;
    // staging source: row = stripe*8 + (lane>>3); col slot pre-swizzled
    const int r8 = lane >> 3, sw = (lane & 7) ^ r8;
    const f16* srcA = A + (bm0 + r8) * KDIM + sw * 8;
    const f16* srcB = B + (bn0 + r8) * KDIM + sw * 8;
    // fragment read offsets (f16 units): row*64 + physslot*8
    const int rA = (wm * 160 + lo) * 64;
    const int rB = (wn * 64 + lo) * 64;
    const int sl0 = (q4 ^ key) * 8;          // kh=0
    const int sl1 = ((q4 | 4) ^ key) * 8;    // kh=1

    // ---- per-wave A-stripe ownership: a_str[0..nA0-1] are P0-need rows
    // (stripes {0..9,20..29}); a_str[nA0..4] are P1-need ({10..19,30..39}).
    int a_str[5], nA0;
    if (wu < 4) {
        nA0 = 3;
        const int b0 = 3 * wu;
        a_str[0] = (b0     < 10) ? b0     : b0 + 10;
        a_str[1] = (b0 + 1 < 10) ? b0 + 1 : b0 + 11;
        a_str[2] = (b0 + 2 < 10) ? b0 + 2 : b0 + 12;
        const int c0 = 2 * wu;               // < 10 always
        a_str[3] = c0 + 10;
        a_str[4] = c0 + 11;
    } else {
        nA0 = 2;
        const int b0 = 12 + 2 * (wu - 4);    // >= 10 always
        a_str[0] = b0 + 10;
        a_str[1] = b0 + 11;
        const int c0 = 8 + 3 * (wu - 4);
        a_str[2] = (c0     < 10) ? c0 + 10 : c0 + 20;
        a_str[3] = (c0 + 1 < 10) ? c0 + 11 : c0 + 21;
        a_str[4] = (c0 + 2 < 10) ? c0 + 12 : c0 + 22;
    }

    f32x4 acc[10][4] = {};

    // prologue: K-tile 0 -> buf 0, in counted issue order [B x4, A x5]
#pragma unroll
    for (int i = 0; i < 4; ++i)
        stage16(&Bs[0][(w + 8 * i) * 512], srcB + (long)(w + 8 * i) * (8 * KDIM));
#pragma unroll
    for (int i = 0; i < 5; ++i)
        stage16(&As[0][a_str[i] * 512], srcA + (long)a_str[i] * (8 * KDIM));
    if (wu < 4) asm volatile("s_waitcnt vmcnt(2)" ::: "memory");
    else        asm volatile("s_waitcnt vmcnt(3)" ::: "memory");
    __builtin_amdgcn_s_barrier();
    asm volatile("" ::: "memory");

    for (int t = 0; t < KDIM / 64; ++t) {
        const int cur = t & 1, nb = cur ^ 1;
        const long k0n = (long)(t + 1) * 64;
        const bool pf = (t + 1 < KDIM / 64);
        const f16* a = As[cur];
        const f16* b = Bs[cur];
        f16x8 af[5], bf[4];
        // -------- P0: kh=0 mh=0; issue next-tile B (4) --------
#pragma unroll
        for (int ni = 0; ni < 4; ++ni) bf[ni] = *(const f16x8*)&b[rB + ni * 1024 + sl0];
#pragma unroll
        for (int i = 0; i < 5; ++i) af[i] = *(const f16x8*)&a[rA + i * 1024 + sl0];
        if (pf) {
#pragma unroll
            for (int i = 0; i < 4; ++i)
                stage16(&Bs[nb][(w + 8 * i) * 512], srcB + (long)(w + 8 * i) * (8 * KDIM) + k0n);
        }
        __builtin_amdgcn_s_setprio(1);
#pragma unroll
        for (int i = 0; i < 5; ++i)
#pragma unroll
            for (int ni = 0; ni < 4; ++ni)
                acc[i][ni] = __builtin_amdgcn_mfma_f32_16x16x32_f16(af[i], bf[ni], acc[i][ni], 0, 0, 0);
        __builtin_amdgcn_s_setprio(0);
        // mid-tile certify: THIS tile's A-P1 landed; 4 new B stay in flight
        if (pf) asm volatile("s_waitcnt vmcnt(4)" ::: "memory");
        else    asm volatile("s_waitcnt vmcnt(0)" ::: "memory");
        __builtin_amdgcn_s_barrier();
        asm volatile("" ::: "memory");
        // -------- P1: kh=0 mh=1; issue next-tile A-P0 (nA0) --------
#pragma unroll
        for (int i = 0; i < 5; ++i) af[i] = *(const f16x8*)&a[rA + (5 + i) * 1024 + sl0];
        if (pf) {
#pragma unroll
            for (int i = 0; i < 5; ++i)
                if (i < nA0)
                    stage16(&As[nb][a_str[i] * 512], srcA + (long)a_str[i] * (8 * KDIM) + k0n);
        }
        __builtin_amdgcn_s_setprio(1);
#pragma unroll
        for (int i = 0; i < 5; ++i)
#pragma unroll
            for (int ni = 0; ni < 4; ++ni)
                acc[5 + i][ni] = __builtin_amdgcn_mfma_f32_16x16x32_f16(af[i], bf[ni], acc[5 + i][ni], 0, 0, 0);
        __builtin_amdgcn_s_setprio(0);
        // -------- P2: kh=1 mh=0; issue next-tile A-P1 (nA1) --------
#pragma unroll
        for (int ni = 0; ni < 4; ++ni) bf[ni] = *(const f16x8*)&b[rB + ni * 1024 + sl1];
#pragma unroll
        for (int i = 0; i < 5; ++i) af[i] = *(const f16x8*)&a[rA + i * 1024 + sl1];
        if (pf) {
#pragma unroll
            for (int i = 0; i < 5; ++i)
                if (i >= nA0)
                    stage16(&As[nb][a_str[i] * 512], srcA + (long)a_str[i] * (8 * KDIM) + k0n);
        }
        __builtin_amdgcn_s_setprio(1);
#pragma unroll
        for (int i = 0; i < 5; ++i)
#pragma unroll
            for (int ni = 0; ni < 4; ++ni)
                acc[i][ni] = __builtin_amdgcn_mfma_f32_16x16x32_f16(af[i], bf[ni], acc[i][ni], 0, 0, 0);
        __builtin_amdgcn_s_setprio(0);
        // -------- P3: kh=1 mh=1 --------
#pragma unroll
        for (int i = 0; i < 5; ++i) af[i] = *(const f16x8*)&a[rA + (5 + i) * 1024 + sl1];
        __builtin_amdgcn_s_setprio(1);
#pragma unroll
        for (int i = 0; i < 5; ++i)
#pragma unroll
            for (int ni = 0; ni < 4; ++ni)
                acc[5 + i][ni] = __builtin_amdgcn_mfma_f32_16x16x32_f16(af[i], bf[ni], acc[5 + i][ni], 0, 0, 0);
        __builtin_amdgcn_s_setprio(0);
        if (pf) {
            // boundary: next tile's B + A-P0 must land; its A-P1 stays in flight
            if (wu < 4) asm volatile("s_waitcnt vmcnt(2)" ::: "memory");
            else        asm volatile("s_waitcnt vmcnt(3)" ::: "memory");
            __builtin_amdgcn_s_barrier();
            asm volatile("" ::: "memory");
        }
    }

#pragma unroll
    for (int mi = 0; mi < 10; ++mi)
#pragma unroll
        for (int ni = 0; ni < 4; ++ni) {
            const long gc = bn0 + wn * 64 + ni * 16 + lo;
            const long gr0 = bm0 + wm * 160 + mi * 16 + q4 * 4;
            if (RES) {
                float* out = (float*)outp;
#pragma unroll
                for (int r = 0; r < 4; ++r) {
                    size_t idx = (size_t)(gr0 + r) * KDIM + gc;
                    out[idx] = acc[mi][ni][r] + resid[idx];
                }
            } else {
                f16* out = (f16*)outp;
#pragma unroll
                for (int r = 0; r < 4; ++r)
                    out[(size_t)(gr0 + r) * KDIM + gc] = (f16)acc[mi][ni][r];
            }
        }
}

// ==== 64x64 bt-GEMM batched, BK=64: attn[b,l,m] = sum_j T[l,j]·qf16[m,j] ===
__global__ __launch_bounds__(256, 2) void attn_gemm(
    const f16* __restrict__ T, const f16* __restrict__ qf16, float* __restrict__ attn) {
    __shared__ f16 As[2 * 64 * 32];
    __shared__ f16 Bs[2 * 64 * 32];
    const int b = blockIdx.z;
    const long tl = (long)blockIdx.y * 64, tmm = (long)blockIdx.x * 64;
    const int tid = threadIdx.x, lane = tid & 63, w = tid >> 6;
    const int wm = w >> 1, wn = w & 1, lo = lane & 15, q4 = lane >> 4;
    const f16* Abase = T + ((long)b * FEAT + tl) * KDIM;
    const f16* Bbase = qf16 + ((long)b * FEAT + tmm) * KDIM;
    const int srow = lane >> 2, sch = (lane & 3) * 8;
    f32x4 acc[2][2] = {};
    for (int k0 = 0; k0 < KDIM; k0 += 64) {
#pragma unroll
        for (int j = 0; j < 2; ++j) {
            const int u = w * 2 + j, h = u & 1, Rb = u >> 1;
            const int base = h * 2048 + Rb * 512;
            const long grow = Rb * 16 + srow;
            const long gk = k0 + h * 32 + sch;
            stage16(&As[base], Abase + grow * KDIM + gk);
            stage16(&Bs[base], Bbase + grow * KDIM + gk);
        }
        __syncthreads();
        f16x8 af[2][2], bf[2][2];
#pragma unroll
        for (int s = 0; s < 2; ++s) {
#pragma unroll
            for (int mi = 0; mi < 2; ++mi)
                af[mi][s] = *(const f16x8*)&As[s * 2048 + (wm * 32 + mi * 16 + lo) * 32 + q4 * 8];
#pragma unroll
            for (int ni = 0; ni < 2; ++ni)
                bf[ni][s] = *(const f16x8*)&Bs[s * 2048 + (wn * 32 + ni * 16 + lo) * 32 + q4 * 8];
        }
#pragma unroll
        for (int s = 0; s < 2; ++s)
#pragma unroll
            for (int mi = 0; mi < 2; ++mi)
#pragma unroll
                for (int ni = 0; ni < 2; ++ni)
                    acc[mi][ni] = __builtin_amdgcn_mfma_f32_16x16x32_f16(af[mi][s], bf[ni][s], acc[mi][ni], 0, 0, 0);
        __syncthreads();
    }
#pragma unroll
    for (int mi = 0; mi < 2; ++mi)
#pragma unroll
        for (int ni = 0; ni < 2; ++ni) {
            long gm = tmm + wn * 32 + ni * 16 + lo;
#pragma unroll
            for (int r = 0; r < 4; ++r) {
                long gl = tl + wm * 32 + mi * 16 + q4 * 4 + r;
                attn[(long)b * (FEAT * FEAT) + gl * FEAT + gm] = acc[mi][ni][r];
            }
        }
}

// == 64x128 bt-GEMM batched, K=320 BK=64: U[b,l,j] = sum_m P[l,m]·qT[j,m] ===
__global__ __launch_bounds__(256, 2) void u_gemm(
    const f16* __restrict__ P, const f16* __restrict__ qT16, f16* __restrict__ U) {
    __shared__ f16 As[2 * 64 * 32];     // 8 KB
    __shared__ f16 Bs[2 * 128 * 32];    // 16 KB
    const int b = blockIdx.z;
    const long tl = (long)blockIdx.y * 64, to = (long)blockIdx.x * 128;
    const int tid = threadIdx.x, lane = tid & 63, w = tid >> 6;
    const int wm = w >> 1, wn = w & 1, lo = lane & 15, q4 = lane >> 4;
    const f16* Abase = P + ((long)b * FEAT + tl) * FEAT;
    const f16* Bbase = qT16 + ((long)b * NPTS + to) * FEAT;
    const int srow = lane >> 2, sch = (lane & 3) * 8;
    f32x4 acc[2][4] = {};
    for (int k0 = 0; k0 < FEAT; k0 += 64) {   // 5 iterations
#pragma unroll
        for (int j = 0; j < 2; ++j) {          // A: 8 wave-units
            const int u = w * 2 + j, h = u & 1, Rb = u >> 1;
            stage16(&As[h * 2048 + Rb * 512],
                    Abase + (long)(Rb * 16 + srow) * FEAT + k0 + h * 32 + sch);
        }
#pragma unroll
        for (int j = 0; j < 4; ++j) {          // B: 16 wave-units
            const int u = w * 4 + j, h = u & 1, Rb = u >> 1;
            stage16(&Bs[h * 4096 + Rb * 512],
                    Bbase + (long)(Rb * 16 + srow) * FEAT + k0 + h * 32 + sch);
        }
        __syncthreads();
        f16x8 af[2][2], bf[4][2];
#pragma unroll
        for (int s = 0; s < 2; ++s) {
#pragma unroll
            for (int mi = 0; mi < 2; ++mi)
                af[mi][s] = *(const f16x8*)&As[s * 2048 + (wm * 32 + mi * 16 + lo) * 32 + q4 * 8];
#pragma unroll
            for (int ni = 0; ni < 4; ++ni)
                bf[ni][s] = *(const f16x8*)&Bs[s * 4096 + (wn * 64 + ni * 16 + lo) * 32 + q4 * 8];
        }
#pragma unroll
        for (int s = 0; s < 2; ++s)
#pragma unroll
            for (int mi = 0; mi < 2; ++mi)
#pragma unroll
                for (int ni = 0; ni < 4; ++ni)
                    acc[mi][ni] = __builtin_amdgcn_mfma_f32_16x16x32_f16(af[mi][s], bf[ni][s], acc[mi][ni], 0, 0, 0);
        __syncthreads();
    }
#pragma unroll
    for (int mi = 0; mi < 2; ++mi)
#pragma unroll
        for (int ni = 0; ni < 4; ++ni) {
            long go = to + wn * 64 + ni * 16 + lo;
#pragma unroll
            for (int r = 0; r < 4; ++r) {
                long gl = tl + wm * 32 + mi * 16 + q4 * 4 + r;
                U[((long)b * FEAT + gl) * NPTS + go] = (f16)acc[mi][ni][r];
            }
        }
}

// ---------------- softmax over rows of 320, fp32 in, f16 probs out ---------
__global__ void softmax_k(const float* __restrict__ attn, f16* __restrict__ probs) {
    const int r = blockIdx.x * 4 + (threadIdx.x >> 6);   // 10240 rows
    const int lane = threadIdx.x & 63;
    const float* row = attn + (size_t)r * FEAT;
    float v[5];
    float mx = -1e30f;
#pragma unroll
    for (int j = 0; j < 5; ++j) { v[j] = row[lane + j * 64]; mx = fmaxf(mx, v[j]); }
#pragma unroll
    for (int off = 32; off; off >>= 1) mx = fmaxf(mx, __shfl_xor(mx, off, 64));
    float s = 0.f;
#pragma unroll
    for (int j = 0; j < 5; ++j) { v[j] = __expf(v[j] - mx); s += v[j]; }
#pragma unroll
    for (int off = 32; off; off >>= 1) s += __shfl_xor(s, off, 64);
    const float inv = 1.f / s;
    f16* prow = probs + (size_t)r * FEAT;
#pragma unroll
    for (int j = 0; j < 5; ++j) prow[lane + j * 64] = (f16)(v[j] * inv);
}

// ---------------- in-place LayerNorm over FEAT (stride NPTS) ---------------
__global__ void ln_k(float* __restrict__ out, const float* __restrict__ gamma,
                     const float* __restrict__ beta) {
    __shared__ float g[FEAT], bt[FEAT];
    const int tid = threadIdx.x;
    for (int i = tid; i < FEAT; i += 256) { g[i] = gamma[i]; bt[i] = beta[i]; }
    __syncthreads();
    const int col = blockIdx.x * 256 + tid;     // 65536 columns
    const int b = col >> 11, o = col & 2047;
    float* base = out + (size_t)b * (FEAT * NPTS) + o;
    float s = 0.f, ss = 0.f;
    for (int l = 0; l < FEAT; ++l) {
        float x = base[(size_t)l * NPTS];
        s += x; ss += x * x;
    }
    const float mu = s * (1.f / FEAT);
    const float var = ss * (1.f / FEAT) - mu * mu;
    const float rstd = rsqrtf(var + 1e-5f);
    for (int l = 0; l < FEAT; ++l) {
        float x = base[(size_t)l * NPTS];
        base[(size_t)l * NPTS] = (x - mu) * rstd * g[l] + bt[l];
    }
}

extern "C" void kernel_launch(void* const* d_in, const int* in_sizes, int n_in,
                              void* d_out, int out_size, void* d_ws, size_t ws_size,
                              hipStream_t stream) {
    const float* query   = (const float*)d_in[0];
    const float* support = (const float*)d_in[1];
    const float* Wq      = (const float*)d_in[2];
    const float* Wk      = (const float*)d_in[3];
    const float* Wv      = (const float*)d_in[4];
    const float* gamma   = (const float*)d_in[5];
    const float* beta    = (const float*)d_in[6];
    float* out = (float*)d_out;

    char* ws = (char*)d_ws;
    const size_t SZ_W = (size_t)KDIM * KDIM * sizeof(f16);   //  8,388,608
    const size_t SZ_X = (size_t)M1 * KDIM * sizeof(f16);     // 41,943,040
    f16* wqT  = (f16*)(ws);                        // [i,o]
    f16* wkT  = (f16*)(ws + SZ_W);                 // [j,o]
    f16* wv16 = (f16*)(ws + 2 * SZ_W);             // [o,j] straight
    f16* gt   = (f16*)(ws + 3 * SZ_W);             // Gt[j,i] = G[i,j]/TEMP
    f16* sf16 = (f16*)(ws + 4 * SZ_W);             // support f16 [b*320, i]
    f16* qf16 = (f16*)(ws + 4 * SZ_W + SZ_X);      // [b,m,j]
    f16* qT16 = (f16*)(ws + 4 * SZ_W + 2 * SZ_X);  // [b,j,m]
    f16* T    = (f16*)(ws + 4 * SZ_W + 3 * SZ_X);  // [b*320, j]
    // overlays (stream-ordered; originals dead by first write):
    float* attn = (float*)(ws);                    // 13.1 MB over wqT+wkT (dead after g_gemm)
    f16*   P    = qf16;                            // probs (qf16 dead after attn_gemm)
    f16*   U    = sf16;                            // U[b,l,j] (sf16 dead after t_gemm)

    const float inv_temp = 0.05590169943749474f;   // 1/sqrt(320)

    castT_k<<<dim3(32, 32, 2), 256, 0, stream>>>(Wq, Wk, wqT, wkT);
    cast_k<<<1024, 256, 0, stream>>>(Wv, wv16, (KDIM * KDIM) / 4);
    cast_k<<<2048, 256, 0, stream>>>(support, sf16, (M1 * KDIM) / 4);
    cast_q_dual<<<dim3(32, 5, 32), 256, 0, stream>>>(query, qf16, qT16);

    // Gt[j,i] = (1/TEMP) * sum_o WkT[j,o] * WqT[i,o]  (2048^2, 256 blocks)
    gemm128_f16<<<dim3(16, 16), 256, 0, stream>>>(wkT, wqT, gt, inv_temp);
    // T[(b,l), j] = sum_i sf16[(b,l), i] * Gt[j, i]  -- counted-vmcnt 320x256
    gemm_big<0><<<dim3(8, 32), 512, 0, stream>>>(sf16, gt, nullptr, T);
    // logits
    attn_gemm<<<dim3(5, 5, 32), 256, 0, stream>>>(T, qf16, attn);
    softmax_k<<<2560, 256, 0, stream>>>(attn, P);
    // U[b,l,j] = sum_m P[b,l,m] * qT16[b,j,m]
    u_gemm<<<dim3(16, 5, 32), 256, 0, stream>>>(P, qT16, U);
    // out = U * Wv^T + query  -- counted-vmcnt 320x256 + residual
    gemm_big<1><<<dim3(8, 32), 512, 0, stream>>>(U, wv16, query, out);
    ln_k<<<256, 256, 0, stream>>>(out, gamma, beta);
}

// Round 4
// 637.603 us; speedup vs baseline: 1.0898x; 1.0363x over previous
//
#include <hip/hip_runtime.h>

typedef _Float16 f16;
typedef _Float16 f16x4 __attribute__((ext_vector_type(4)));
typedef _Float16 f16x8 __attribute__((ext_vector_type(8)));
typedef float    f32x4 __attribute__((ext_vector_type(4)));

#define NB    32
#define FEAT  320
#define NPTS  2048
#define M1    (NB * FEAT)          // 10240
#define KDIM  2048

// async global->LDS, 16B per lane. LDS dest = wave-uniform base + lane*16.
__device__ __forceinline__ void stage16(f16* lds_base, const f16* g) {
    __builtin_amdgcn_global_load_lds(
        (const __attribute__((address_space(1))) void*)g,
        (__attribute__((address_space(3))) void*)lds_base, 16, 0, 0);
}

// ---------------- cast fp32 -> f16 (two buffers in one launch) -------------
__global__ void cast2_k(const float* __restrict__ a, f16* __restrict__ da, int n4a,
                        const float* __restrict__ b, f16* __restrict__ db, int n4b) {
    int i = blockIdx.x * blockDim.x + threadIdx.x;
    int stride = gridDim.x * blockDim.x;
    for (; i < n4a + n4b; i += stride) {
        if (i < n4a) {
            f32x4 v = *(const f32x4*)(a + (size_t)i * 4);
            *(f16x4*)(da + (size_t)i * 4) = __builtin_convertvector(v, f16x4);
        } else {
            size_t j = (size_t)(i - n4a);
            f32x4 v = *(const f32x4*)(b + j * 4);
            *(f16x4*)(db + j * 4) = __builtin_convertvector(v, f16x4);
        }
    }
}

// ------------- transpose-cast W [o,i] fp32 -> WT [i,o] f16, z picks Wq/Wk --
__global__ void castT_k(const float* __restrict__ Wq, const float* __restrict__ Wk,
                        f16* __restrict__ WqT, f16* __restrict__ WkT) {
    __shared__ float T[64][65];
    const float* W = blockIdx.z ? Wk : Wq;
    f16* WT        = blockIdx.z ? WkT : WqT;
    const int i0 = blockIdx.x * 64, o0 = blockIdx.y * 64;
    const int tid = threadIdx.x;
#pragma unroll
    for (int j = 0; j < 4; ++j) {
        int e = j * 256 + tid, r = e >> 4, c4 = e & 15;
        f32x4 v = *(const f32x4*)&W[(size_t)(o0 + r) * 2048 + i0 + c4 * 4];
        *(f32x4*)&T[r][c4 * 4] = v;
    }
    __syncthreads();
#pragma unroll
    for (int j = 0; j < 2; ++j) {
        int e = j * 256 + tid, ir = e >> 3, oc8 = e & 7;
        f16x8 val;
#pragma unroll
        for (int k = 0; k < 8; ++k) val[k] = (f16)T[oc8 * 8 + k][ir];
        *(f16x8*)&WT[(size_t)(i0 + ir) * 2048 + o0 + oc8 * 8] = val;
    }
}

// ------- query [b,m,j] fp32 -> qf16 [b,m,j] + qT16 [b,j,m], both f16 -------
__global__ void cast_q_dual(const float* __restrict__ q, f16* __restrict__ qf16,
                            f16* __restrict__ qT16) {
    __shared__ float T[64][65];
    const int b = blockIdx.z;
    const int j0 = blockIdx.x * 64, m0 = blockIdx.y * 64;  // m0 in [0,320)
    const int tid = threadIdx.x;
#pragma unroll
    for (int j = 0; j < 4; ++j) {
        int e = j * 256 + tid, r = e >> 4, c4 = e & 15;
        size_t src = ((size_t)b * FEAT + m0 + r) * NPTS + j0 + c4 * 4;
        f32x4 v = *(const f32x4*)&q[src];
        *(f32x4*)&T[r][c4 * 4] = v;
        *(f16x4*)&qf16[src] = __builtin_convertvector(v, f16x4);
    }
    __syncthreads();
#pragma unroll
    for (int j = 0; j < 2; ++j) {
        int e = j * 256 + tid, jr = e >> 3, mc8 = e & 7;
        f16x8 val;
#pragma unroll
        for (int k = 0; k < 8; ++k) val[k] = (f16)T[mc8 * 8 + k][jr];
        *(f16x8*)&qT16[((size_t)b * NPTS + j0 + jr) * FEAT + m0 + mc8 * 8] = val;
    }
}

// ======== 128x128 bt-GEMM, BK=64 (split-k-half LDS): C = scale*A·B^T =======
// (kept for the 2048x2048 Gt GEMM: grid 16x16 = 256 blocks, already balanced)
__global__ __launch_bounds__(256, 2) void gemm128_f16(
    const f16* __restrict__ A, const f16* __restrict__ B, f16* __restrict__ C,
    float scale) {
    __shared__ f16 As[2 * 128 * 32];
    __shared__ f16 Bs[2 * 128 * 32];
    const int tid = threadIdx.x, lane = tid & 63, w = tid >> 6;
    const int wm = w >> 1, wn = w & 1, lo = lane & 15, q4 = lane >> 4;
    const long tm = (long)blockIdx.y * 128, tn = (long)blockIdx.x * 128;
    const f16* Abase = A + tm * KDIM;
    const f16* Bbase = B + tn * KDIM;
    f32x4 acc[4][4] = {};
    const int srow = lane >> 2, sch = (lane & 3) * 8;

    for (int k0 = 0; k0 < KDIM; k0 += 64) {
#pragma unroll
        for (int j = 0; j < 4; ++j) {
            const int u = w * 4 + j, h = u & 1, Rb = u >> 1;
            const int base = h * 4096 + Rb * 512;
            const long grow = Rb * 16 + srow;
            const long gk = k0 + h * 32 + sch;
            stage16(&As[base], Abase + grow * KDIM + gk);
            stage16(&Bs[base], Bbase + grow * KDIM + gk);
        }
        __syncthreads();
        f16x8 af[4][2], bf[4][2];
#pragma unroll
        for (int s = 0; s < 2; ++s) {
#pragma unroll
            for (int mi = 0; mi < 4; ++mi)
                af[mi][s] = *(const f16x8*)&As[s * 4096 + (wm * 64 + mi * 16 + lo) * 32 + q4 * 8];
#pragma unroll
            for (int ni = 0; ni < 4; ++ni)
                bf[ni][s] = *(const f16x8*)&Bs[s * 4096 + (wn * 64 + ni * 16 + lo) * 32 + q4 * 8];
        }
#pragma unroll
        for (int s = 0; s < 2; ++s)
#pragma unroll
            for (int mi = 0; mi < 4; ++mi)
#pragma unroll
                for (int ni = 0; ni < 4; ++ni)
                    acc[mi][ni] = __builtin_amdgcn_mfma_f32_16x16x32_f16(af[mi][s], bf[ni][s], acc[mi][ni], 0, 0, 0);
        __syncthreads();
    }
#pragma unroll
    for (int mi = 0; mi < 4; ++mi)
#pragma unroll
        for (int ni = 0; ni < 4; ++ni) {
            long gc = tn + wn * 64 + ni * 16 + lo;
#pragma unroll
            for (int r = 0; r < 4; ++r) {
                long gr = tm + wm * 64 + mi * 16 + q4 * 4 + r;
                C[gr * KDIM + gc] = (f16)(acc[mi][ni][r] * scale);
            }
        }
}

// ======= 320x128 8-wave GEMM: C = A·B^T, K = 2048, full-tile frag preload ==
// BM=320 BN=128 BK=64; grid (16,32) = 512 blocks = exactly 2 rounds/256 CU.
// Wave (4M x 2N) = 80x64 out -> acc[5][4] = 80 regs; frags 18 x f16x8 = 72;
// ~200 regs/wave total -> 2 waves/SIMD guaranteed under any RF model.
// Body: barrier -> issue ALL next-tile stages (7) -> issue ALL 18 ds_reads
// -> MFMA kh0 (20) -> MFMA kh1 (20, reads covered by kh0 cluster) ->
// vmcnt(0)+barrier (stages were issued ~full body earlier: drain is cheap).
// T2 swizzle: phys 16B slot = logical ^ (row&7); linear LDS dest +
// pre-swizzled global source; same XOR on ds_read. T5 setprio on MFMA.
// RES=1 additionally fuses residual add + LayerNorm over FEAT: block =
// all 320 rows of one batch x 128 cols -> LN is block-local (LDS reduce).
template<int RES>
__global__ __launch_bounds__(512, 2) void gemm_big(
    const f16* __restrict__ A, const f16* __restrict__ B,
    const float* __restrict__ resid, void* __restrict__ outp,
    const float* __restrict__ gamma, const float* __restrict__ beta) {
    __shared__ f16 As[2][320 * 64];       // 80 KB
    __shared__ f16 Bs[2][128 * 64];       // 32 KB
    __shared__ float lnbuf[4][128][2];    // 4 KB  (RES=1 column sums)
    __shared__ float gb[2][FEAT];         // 2.5 KB (gamma/beta)
    const int tid = threadIdx.x, lane = tid & 63, w = tid >> 6;
    const int wm = w >> 1, wn = w & 1, lo = lane & 15, q4 = lane >> 4;
    const int key = lo & 7;
    const long bm0 = (long)blockIdx.y * 320, bn0 = (long)blockIdx.x * 128;
    // staging source: row = stripe*8 + (lane>>3); col slot pre-swizzled
    const int r8 = lane >> 3, sw = (lane & 7) ^ r8;
    const f16* srcA = A + (bm0 + r8) * KDIM + sw * 8;
    const f16* srcB = B + (bn0 + r8) * KDIM + sw * 8;
    // fragment read offsets (f16 units): row*64 + physslot*8
    const int rA = (wm * 80 + lo) * 64;
    const int rB = (wn * 64 + lo) * 64;
    const int sl0 = (q4 ^ key) * 8;          // kh=0
    const int sl1 = ((q4 | 4) ^ key) * 8;    // kh=1

    f32x4 acc[5][4] = {};

    if (RES) {
        for (int i = tid; i < FEAT; i += 512) { gb[0][i] = gamma[i]; gb[1][i] = beta[i]; }
    }

    // prologue: K-tile 0 -> buf 0 (per wave: 2 B stripes + 5 A stripes)
#pragma unroll
    for (int i = 0; i < 2; ++i)
        stage16(&Bs[0][(w + 8 * i) * 512], srcB + (long)(w + 8 * i) * (8 * KDIM));
#pragma unroll
    for (int i = 0; i < 5; ++i)
        stage16(&As[0][(w + 8 * i) * 512], srcA + (long)(w + 8 * i) * (8 * KDIM));
    asm volatile("s_waitcnt vmcnt(0)" ::: "memory");
    __builtin_amdgcn_s_barrier();
    asm volatile("" ::: "memory");

    for (int t = 0; t < KDIM / 64; ++t) {
        const int cur = t & 1, nb = cur ^ 1;
        const long k0n = (long)(t + 1) * 64;
        const bool pf = (t + 1 < KDIM / 64);
        // ---- issue next-tile stages FIRST (max drain cover) ----
        if (pf) {
#pragma unroll
            for (int i = 0; i < 2; ++i)
                stage16(&Bs[nb][(w + 8 * i) * 512], srcB + (long)(w + 8 * i) * (8 * KDIM) + k0n);
#pragma unroll
            for (int i = 0; i < 5; ++i)
                stage16(&As[nb][(w + 8 * i) * 512], srcA + (long)(w + 8 * i) * (8 * KDIM) + k0n);
        }
        // ---- all 18 fragment reads for BOTH k-halves ----
        const f16* a = As[cur];
        const f16* b = Bs[cur];
        f16x8 af0[5], af1[5], bf0[4], bf1[4];
#pragma unroll
        for (int ni = 0; ni < 4; ++ni) bf0[ni] = *(const f16x8*)&b[rB + ni * 1024 + sl0];
#pragma unroll
        for (int i = 0; i < 5; ++i)    af0[i] = *(const f16x8*)&a[rA + i * 1024 + sl0];
#pragma unroll
        for (int ni = 0; ni < 4; ++ni) bf1[ni] = *(const f16x8*)&b[rB + ni * 1024 + sl1];
#pragma unroll
        for (int i = 0; i < 5; ++i)    af1[i] = *(const f16x8*)&a[rA + i * 1024 + sl1];
        // ---- MFMA kh0 ----
        __builtin_amdgcn_s_setprio(1);
#pragma unroll
        for (int i = 0; i < 5; ++i)
#pragma unroll
            for (int ni = 0; ni < 4; ++ni)
                acc[i][ni] = __builtin_amdgcn_mfma_f32_16x16x32_f16(af0[i], bf0[ni], acc[i][ni], 0, 0, 0);
        __builtin_amdgcn_s_setprio(0);
        // ---- MFMA kh1 (reads covered by kh0 cluster) ----
        __builtin_amdgcn_s_setprio(1);
#pragma unroll
        for (int i = 0; i < 5; ++i)
#pragma unroll
            for (int ni = 0; ni < 4; ++ni)
                acc[i][ni] = __builtin_amdgcn_mfma_f32_16x16x32_f16(af1[i], bf1[ni], acc[i][ni], 0, 0, 0);
        __builtin_amdgcn_s_setprio(0);
        if (pf) {
            asm volatile("s_waitcnt vmcnt(0)" ::: "memory");
            __builtin_amdgcn_s_barrier();
            asm volatile("" ::: "memory");
        }
    }

    if (RES) {
        float* out = (float*)outp;
        // residual add into acc
#pragma unroll
        for (int mi = 0; mi < 5; ++mi)
#pragma unroll
            for (int ni = 0; ni < 4; ++ni) {
                const long gc = bn0 + wn * 64 + ni * 16 + lo;
                const long gr0 = bm0 + wm * 80 + mi * 16 + q4 * 4;
#pragma unroll
                for (int r = 0; r < 4; ++r)
                    acc[mi][ni][r] += resid[(size_t)(gr0 + r) * KDIM + gc];
            }
        // per-lane partial column sums (20 rows per lane per column)
        float s[4] = {}, ss[4] = {};
#pragma unroll
        for (int mi = 0; mi < 5; ++mi)
#pragma unroll
            for (int ni = 0; ni < 4; ++ni)
#pragma unroll
                for (int r = 0; r < 4; ++r) {
                    float v = acc[mi][ni][r];
                    s[ni] += v; ss[ni] += v * v;
                }
        // reduce across q4 groups (same lo)
#pragma unroll
        for (int ni = 0; ni < 4; ++ni) {
            s[ni]  += __shfl_xor(s[ni], 16, 64);  s[ni]  += __shfl_xor(s[ni], 32, 64);
            ss[ni] += __shfl_xor(ss[ni], 16, 64); ss[ni] += __shfl_xor(ss[ni], 32, 64);
        }
        if (q4 == 0) {
#pragma unroll
            for (int ni = 0; ni < 4; ++ni) {
                int c = wn * 64 + ni * 16 + lo;
                lnbuf[wm][c][0] = s[ni];
                lnbuf[wm][c][1] = ss[ni];
            }
        }
        __syncthreads();
        float mu[4], rstd[4];
#pragma unroll
        for (int ni = 0; ni < 4; ++ni) {
            int c = wn * 64 + ni * 16 + lo;
            float S = lnbuf[0][c][0] + lnbuf[1][c][0] + lnbuf[2][c][0] + lnbuf[3][c][0];
            float SS = lnbuf[0][c][1] + lnbuf[1][c][1] + lnbuf[2][c][1] + lnbuf[3][c][1];
            mu[ni] = S * (1.0f / FEAT);
            float var = SS * (1.0f / FEAT) - mu[ni] * mu[ni];
            rstd[ni] = rsqrtf(var + 1e-5f);
        }
#pragma unroll
        for (int mi = 0; mi < 5; ++mi)
#pragma unroll
            for (int ni = 0; ni < 4; ++ni) {
                const long gc = bn0 + wn * 64 + ni * 16 + lo;
                const long gr0 = bm0 + wm * 80 + mi * 16 + q4 * 4;
#pragma unroll
                for (int r = 0; r < 4; ++r) {
                    int l = wm * 80 + mi * 16 + q4 * 4 + r;   // row within batch
                    out[(size_t)(gr0 + r) * KDIM + gc] =
                        (acc[mi][ni][r] - mu[ni]) * rstd[ni] * gb[0][l] + gb[1][l];
                }
            }
    } else {
        f16* out = (f16*)outp;
#pragma unroll
        for (int mi = 0; mi < 5; ++mi)
#pragma unroll
            for (int ni = 0; ni < 4; ++ni) {
                const long gc = bn0 + wn * 64 + ni * 16 + lo;
                const long gr0 = bm0 + wm * 80 + mi * 16 + q4 * 4;
#pragma unroll
                for (int r = 0; r < 4; ++r)
                    out[(size_t)(gr0 + r) * KDIM + gc] = (f16)acc[mi][ni][r];
            }
    }
}

// ==== 64x64 bt-GEMM batched, BK=64: attn[b,l,m] = sum_j T[l,j]·qf16[m,j] ===
__global__ __launch_bounds__(256, 2) void attn_gemm(
    const f16* __restrict__ T, const f16* __restrict__ qf16, float* __restrict__ attn) {
    __shared__ f16 As[2 * 64 * 32];
    __shared__ f16 Bs[2 * 64 * 32];
    const int b = blockIdx.z;
    const long tl = (long)blockIdx.y * 64, tmm = (long)blockIdx.x * 64;
    const int tid = threadIdx.x, lane = tid & 63, w = tid >> 6;
    const int wm = w >> 1, wn = w & 1, lo = lane & 15, q4 = lane >> 4;
    const f16* Abase = T + ((long)b * FEAT + tl) * KDIM;
    const f16* Bbase = qf16 + ((long)b * FEAT + tmm) * KDIM;
    const int srow = lane >> 2, sch = (lane & 3) * 8;
    f32x4 acc[2][2] = {};
    for (int k0 = 0; k0 < KDIM; k0 += 64) {
#pragma unroll
        for (int j = 0; j < 2; ++j) {
            const int u = w * 2 + j, h = u & 1, Rb = u >> 1;
            const int base = h * 2048 + Rb * 512;
            const long grow = Rb * 16 + srow;
            const long gk = k0 + h * 32 + sch;
            stage16(&As[base], Abase + grow * KDIM + gk);
            stage16(&Bs[base], Bbase + grow * KDIM + gk);
        }
        __syncthreads();
        f16x8 af[2][2], bf[2][2];
#pragma unroll
        for (int s = 0; s < 2; ++s) {
#pragma unroll
            for (int mi = 0; mi < 2; ++mi)
                af[mi][s] = *(const f16x8*)&As[s * 2048 + (wm * 32 + mi * 16 + lo) * 32 + q4 * 8];
#pragma unroll
            for (int ni = 0; ni < 2; ++ni)
                bf[ni][s] = *(const f16x8*)&Bs[s * 2048 + (wn * 32 + ni * 16 + lo) * 32 + q4 * 8];
        }
#pragma unroll
        for (int s = 0; s < 2; ++s)
#pragma unroll
            for (int mi = 0; mi < 2; ++mi)
#pragma unroll
                for (int ni = 0; ni < 2; ++ni)
                    acc[mi][ni] = __builtin_amdgcn_mfma_f32_16x16x32_f16(af[mi][s], bf[ni][s], acc[mi][ni], 0, 0, 0);
        __syncthreads();
    }
#pragma unroll
    for (int mi = 0; mi < 2; ++mi)
#pragma unroll
        for (int ni = 0; ni < 2; ++ni) {
            long gm = tmm + wn * 32 + ni * 16 + lo;
#pragma unroll
            for (int r = 0; r < 4; ++r) {
                long gl = tl + wm * 32 + mi * 16 + q4 * 4 + r;
                attn[(long)b * (FEAT * FEAT) + gl * FEAT + gm] = acc[mi][ni][r];
            }
        }
}

// == 64x128 bt-GEMM batched, K=320 BK=64: U[b,l,j] = sum_m P[l,m]·qT[j,m] ===
__global__ __launch_bounds__(256, 2) void u_gemm(
    const f16* __restrict__ P, const f16* __restrict__ qT16, f16* __restrict__ U) {
    __shared__ f16 As[2 * 64 * 32];     // 8 KB
    __shared__ f16 Bs[2 * 128 * 32];    // 16 KB
    const int b = blockIdx.z;
    const long tl = (long)blockIdx.y * 64, to = (long)blockIdx.x * 128;
    const int tid = threadIdx.x, lane = tid & 63, w = tid >> 6;
    const int wm = w >> 1, wn = w & 1, lo = lane & 15, q4 = lane >> 4;
    const f16* Abase = P + ((long)b * FEAT + tl) * FEAT;
    const f16* Bbase = qT16 + ((long)b * NPTS + to) * FEAT;
    const int srow = lane >> 2, sch = (lane & 3) * 8;
    f32x4 acc[2][4] = {};
    for (int k0 = 0; k0 < FEAT; k0 += 64) {   // 5 iterations
#pragma unroll
        for (int j = 0; j < 2; ++j) {          // A: 8 wave-units
            const int u = w * 2 + j, h = u & 1, Rb = u >> 1;
            stage16(&As[h * 2048 + Rb * 512],
                    Abase + (long)(Rb * 16 + srow) * FEAT + k0 + h * 32 + sch);
        }
#pragma unroll
        for (int j = 0; j < 4; ++j) {          // B: 16 wave-units
            const int u = w * 4 + j, h = u & 1, Rb = u >> 1;
            stage16(&Bs[h * 4096 + Rb * 512],
                    Bbase + (long)(Rb * 16 + srow) * FEAT + k0 + h * 32 + sch);
        }
        __syncthreads();
        f16x8 af[2][2], bf[4][2];
#pragma unroll
        for (int s = 0; s < 2; ++s) {
#pragma unroll
            for (int mi = 0; mi < 2; ++mi)
                af[mi][s] = *(const f16x8*)&As[s * 2048 + (wm * 32 + mi * 16 + lo) * 32 + q4 * 8];
#pragma unroll
            for (int ni = 0; ni < 4; ++ni)
                bf[ni][s] = *(const f16x8*)&Bs[s * 4096 + (wn * 64 + ni * 16 + lo) * 32 + q4 * 8];
        }
#pragma unroll
        for (int s = 0; s < 2; ++s)
#pragma unroll
            for (int mi = 0; mi < 2; ++mi)
#pragma unroll
                for (int ni = 0; ni < 4; ++ni)
                    acc[mi][ni] = __builtin_amdgcn_mfma_f32_16x16x32_f16(af[mi][s], bf[ni][s], acc[mi][ni], 0, 0, 0);
        __syncthreads();
    }
#pragma unroll
    for (int mi = 0; mi < 2; ++mi)
#pragma unroll
        for (int ni = 0; ni < 4; ++ni) {
            long go = to + wn * 64 + ni * 16 + lo;
#pragma unroll
            for (int r = 0; r < 4; ++r) {
                long gl = tl + wm * 32 + mi * 16 + q4 * 4 + r;
                U[((long)b * FEAT + gl) * NPTS + go] = (f16)acc[mi][ni][r];
            }
        }
}

// ---------------- softmax over rows of 320, fp32 in, f16 probs out ---------
__global__ void softmax_k(const float* __restrict__ attn, f16* __restrict__ probs) {
    const int r = blockIdx.x * 4 + (threadIdx.x >> 6);   // 10240 rows
    const int lane = threadIdx.x & 63;
    const float* row = attn + (size_t)r * FEAT;
    float v[5];
    float mx = -1e30f;
#pragma unroll
    for (int j = 0; j < 5; ++j) { v[j] = row[lane + j * 64]; mx = fmaxf(mx, v[j]); }
#pragma unroll
    for (int off = 32; off; off >>= 1) mx = fmaxf(mx, __shfl_xor(mx, off, 64));
    float s = 0.f;
#pragma unroll
    for (int j = 0; j < 5; ++j) { v[j] = __expf(v[j] - mx); s += v[j]; }
#pragma unroll
    for (int off = 32; off; off >>= 1) s += __shfl_xor(s, off, 64);
    const float inv = 1.f / s;
    f16* prow = probs + (size_t)r * FEAT;
#pragma unroll
    for (int j = 0; j < 5; ++j) prow[lane + j * 64] = (f16)(v[j] * inv);
}

extern "C" void kernel_launch(void* const* d_in, const int* in_sizes, int n_in,
                              void* d_out, int out_size, void* d_ws, size_t ws_size,
                              hipStream_t stream) {
    const float* query   = (const float*)d_in[0];
    const float* support = (const float*)d_in[1];
    const float* Wq      = (const float*)d_in[2];
    const float* Wk      = (const float*)d_in[3];
    const float* Wv      = (const float*)d_in[4];
    const float* gamma   = (const float*)d_in[5];
    const float* beta    = (const float*)d_in[6];
    float* out = (float*)d_out;

    char* ws = (char*)d_ws;
    const size_t SZ_W = (size_t)KDIM * KDIM * sizeof(f16);   //  8,388,608
    const size_t SZ_X = (size_t)M1 * KDIM * sizeof(f16);     // 41,943,040
    f16* wqT  = (f16*)(ws);                        // [i,o]
    f16* wkT  = (f16*)(ws + SZ_W);                 // [j,o]
    f16* wv16 = (f16*)(ws + 2 * SZ_W);             // [o,j] straight
    f16* gt   = (f16*)(ws + 3 * SZ_W);             // Gt[j,i] = G[i,j]/TEMP
    f16* sf16 = (f16*)(ws + 4 * SZ_W);             // support f16 [b*320, i]
    f16* qf16 = (f16*)(ws + 4 * SZ_W + SZ_X);      // [b,m,j]
    f16* qT16 = (f16*)(ws + 4 * SZ_W + 2 * SZ_X);  // [b,j,m]
    f16* T    = (f16*)(ws + 4 * SZ_W + 3 * SZ_X);  // [b*320, j]
    // overlays (stream-ordered; originals dead by first write):
    float* attn = (float*)(ws);                    // 13.1 MB over wqT+wkT (dead after g_gemm)
    f16*   P    = qf16;                            // probs (qf16 dead after attn_gemm)
    f16*   U    = sf16;                            // U[b,l,j] (sf16 dead after t_gemm)

    const float inv_temp = 0.05590169943749474f;   // 1/sqrt(320)

    castT_k<<<dim3(32, 32, 2), 256, 0, stream>>>(Wq, Wk, wqT, wkT);
    cast2_k<<<2048, 256, 0, stream>>>(Wv, wv16, (KDIM * KDIM) / 4,
                                      support, sf16, (M1 * KDIM) / 4);
    cast_q_dual<<<dim3(32, 5, 32), 256, 0, stream>>>(query, qf16, qT16);

    // Gt[j,i] = (1/TEMP) * sum_o WkT[j,o] * WqT[i,o]  (2048^2, 256 blocks)
    gemm128_f16<<<dim3(16, 16), 256, 0, stream>>>(wkT, wqT, gt, inv_temp);
    // T[(b,l), j] = sum_i sf16[(b,l), i] * Gt[j, i]  -- 320x128 preload GEMM
    gemm_big<0><<<dim3(16, 32), 512, 0, stream>>>(sf16, gt, nullptr, T, nullptr, nullptr);
    // logits
    attn_gemm<<<dim3(5, 5, 32), 256, 0, stream>>>(T, qf16, attn);
    softmax_k<<<2560, 256, 0, stream>>>(attn, P);
    // U[b,l,j] = sum_m P[b,l,m] * qT16[b,j,m]
    u_gemm<<<dim3(16, 5, 32), 256, 0, stream>>>(P, qT16, U);
    // out = LayerNorm(U * Wv^T + query)  -- fused epilogue
    gemm_big<1><<<dim3(16, 32), 512, 0, stream>>>(U, wv16, query, out, gamma, beta);
}